// Round 1
// baseline (3137.619 us; speedup 1.0000x reference)
//
#include <hip/hip_runtime.h>
#include <math.h>

#define H 256
#define TILE 8
#define BK 16

// ---------------- gather initial: data[i] = x[map[i]] ----------------
__global__ __launch_bounds__(256) void gather_x_kernel(const float4* __restrict__ x,
                                                       const int* __restrict__ map,
                                                       float4* __restrict__ out, int n) {
  int total = n * (H / 4);
  for (int idx = blockIdx.x * blockDim.x + threadIdx.x; idx < total;
       idx += gridDim.x * blockDim.x) {
    int e = idx >> 6;  // H/4 = 64 float4 per row
    int q = idx & 63;
    out[idx] = x[(size_t)map[e] * 64 + q];
  }
}

// ---------------- transpose weight: Wt[k][h][o] = W[k][o][h] ----------------
__global__ __launch_bounds__(256) void transpose_w_kernel(const float* __restrict__ W,
                                                          float* __restrict__ Wt) {
  __shared__ float tile[32][33];
  int k = blockIdx.z;
  int o0 = blockIdx.x * 32, h0 = blockIdx.y * 32;
  int tx = threadIdx.x, ty = threadIdx.y;
  for (int r = ty; r < 32; r += 8)
    tile[r][tx] = W[(size_t)k * H * H + (size_t)(o0 + r) * H + (h0 + tx)];
  __syncthreads();
  for (int r = ty; r < 32; r += 8)
    Wt[(size_t)k * H * H + (size_t)(h0 + r) * H + (o0 + tx)] = tile[tx][r];
}

// ---------------- bucket rows by type + segment-max of tmask ----------------
__global__ __launch_bounds__(256) void bucket_kernel(const int* __restrict__ tmask,
                                                     const int* __restrict__ pool,
                                                     int* __restrict__ lists,
                                                     int* __restrict__ counts,
                                                     int* __restrict__ tm2, int m,
                                                     int listStride) {
  int i = blockIdx.x * blockDim.x + threadIdx.x;
  if (i >= m) return;
  int t = tmask[i];
  int p = atomicAdd(&counts[t], 1);
  lists[t * listStride + p] = i;
  atomicMax(&tm2[pool[i]], t);
}

// ---------------- type 0: pooled[seg] += child0 row ----------------
__global__ __launch_bounds__(256) void type0_kernel(const float* __restrict__ data,
                                                    const int* __restrict__ om,
                                                    const int* __restrict__ list,
                                                    const int* __restrict__ count,
                                                    const int* __restrict__ pool,
                                                    float* __restrict__ pooled, int m) {
  int n = *count;
  int total = n * H;
  for (int idx = blockIdx.x * blockDim.x + threadIdx.x; idx < total;
       idx += gridDim.x * blockDim.x) {
    int e = idx >> 8;
    int o = idx & (H - 1);
    int row = list[e];
    int c = om[row];  // child 0
    if (c >= 0) {
      float v = data[(size_t)c * H + o];
      atomicAdd(&pooled[(size_t)pool[row] * H + o], v);
    }
  }
}

// ---------------- generic bucketed GEMM ----------------
// NCH children summed through Wt (NCH*H x H, [kh][o] layout), optional second
// GEMM through Wt2 (H x H). Output accumulated atomically into pooled[pool[row]]
// or written directly to outp[row].
template <int NCH, bool TWO, bool USE_OM, bool ATOMIC_OUT>
__global__ __launch_bounds__(256) void tree_gemm(const float* __restrict__ data,
                                                 const int* __restrict__ om,
                                                 const int* __restrict__ list,
                                                 const int* __restrict__ count,
                                                 const int* __restrict__ pool,
                                                 const float* __restrict__ Wt,
                                                 const float* __restrict__ Wt2,
                                                 float* __restrict__ outp, int m) {
  const int t = threadIdx.x;
  __shared__ float sA[TILE][NCH * H];
  __shared__ float sB[BK][H];
  __shared__ float sC[TWO ? TILE : 1][H];
  __shared__ int sRow[TILE];

  int n = count[0];
  int base = blockIdx.x * TILE;
  if (base >= n) return;

  if (t < TILE) sRow[t] = (base + t < n) ? list[base + t] : -1;
  __syncthreads();

  // stage A (gathered child rows), zero for missing
  for (int j = 0; j < TILE; ++j) {
    int row = sRow[j];
#pragma unroll
    for (int k = 0; k < NCH; ++k) {
      float v = 0.f;
      if (row >= 0) {
        if (USE_OM) {
          int c = om[k * m + row];
          if (c >= 0) v = data[(size_t)c * H + t];
        } else {
          v = data[(size_t)row * H + t];
        }
      }
      sA[j][k * H + t] = v;
    }
  }
  __syncthreads();

  float acc[TILE];
#pragma unroll
  for (int j = 0; j < TILE; ++j) acc[j] = 0.f;

  for (int kk = 0; kk < NCH * H; kk += BK) {
#pragma unroll
    for (int i = 0; i < BK; ++i) sB[i][t] = Wt[(size_t)(kk + i) * H + t];
    __syncthreads();
#pragma unroll
    for (int i = 0; i < BK; ++i) {
      float b = sB[i][t];
#pragma unroll
      for (int j = 0; j < TILE; ++j) acc[j] = fmaf(sA[j][kk + i], b, acc[j]);
    }
    __syncthreads();
  }

  if (TWO) {
#pragma unroll
    for (int j = 0; j < TILE; ++j) sC[j][t] = acc[j];
    __syncthreads();
#pragma unroll
    for (int j = 0; j < TILE; ++j) acc[j] = 0.f;
    for (int kk = 0; kk < H; kk += BK) {
#pragma unroll
      for (int i = 0; i < BK; ++i) sB[i][t] = Wt2[(size_t)(kk + i) * H + t];
      __syncthreads();
#pragma unroll
      for (int i = 0; i < BK; ++i) {
        float b = sB[i][t];
#pragma unroll
        for (int j = 0; j < TILE; ++j) acc[j] = fmaf(sC[j][kk + i], b, acc[j]);
      }
      __syncthreads();
    }
  }

  for (int j = 0; j < TILE; ++j) {
    int row = sRow[j];
    if (row < 0) continue;
    if (ATOMIC_OUT) {
      atomicAdd(&outp[(size_t)pool[row] * H + t], acc[j]);
    } else {
      outp[(size_t)row * H + t] = acc[j];
    }
  }
}

// ---------------- ELU where tm2 != 0; bucket tm2 == 1 segments ----------------
__global__ __launch_bounds__(256) void elu_bucket_kernel(float* __restrict__ pooled,
                                                         const int* __restrict__ tm2,
                                                         int* __restrict__ listF,
                                                         int* __restrict__ countF, int g) {
  int s = blockIdx.x;
  if (s >= g) return;
  int t2 = tm2[s];
  int t = threadIdx.x;
  if (t2 != 0) {
    float v = pooled[(size_t)s * H + t];
    pooled[(size_t)s * H + t] = v > 0.f ? v : (expf(v) - 1.f);
  }
  if (t2 == 1 && t == 0) {
    int p = atomicAdd(countF, 1);
    listF[p] = s;
  }
}

// ---------------- host driver ----------------
extern "C" void kernel_launch(void* const* d_in, const int* in_sizes, int n_in,
                              void* d_out, int out_size, void* d_ws, size_t ws_size,
                              hipStream_t stream) {
  const float* x = (const float*)d_in[0];
  const int* initial_map = (const int*)d_in[1];
  const int* om[3] = {(const int*)d_in[2], (const int*)d_in[5], (const int*)d_in[8]};
  const int* pool[3] = {(const int*)d_in[3], (const int*)d_in[6], (const int*)d_in[9]};
  const int* tmask[3] = {(const int*)d_in[4], (const int*)d_in[7], (const int*)d_in[10]};
  const float* W_z = (const float*)d_in[11];
  const float* W_z_int = (const float*)d_in[12];
  const float* W_s = (const float*)d_in[13];
  const float* W_s_int = (const float*)d_in[14];
  const float* W_p = (const float*)d_in[15];
  const float* W_pf = (const float*)d_in[16];

  char* ws = (char*)d_ws;
  float* dataA = (float*)ws; ws += (size_t)65536 * H * 4;       // 64 MB
  float* dataB = (float*)ws; ws += (size_t)32768 * H * 4;       // 32 MB
  float* Wt_z = (float*)ws; ws += (size_t)4 * H * H * 4;
  float* Wt_zint = (float*)ws; ws += (size_t)H * H * 4;
  float* Wt_s = (float*)ws; ws += (size_t)4 * H * H * 4;
  float* Wt_sint = (float*)ws; ws += (size_t)H * H * 4;
  float* Wt_p = (float*)ws; ws += (size_t)H * H * 4;
  float* Wt_pf = (float*)ws; ws += (size_t)H * H * 4;
  int* lists = (int*)ws; ws += (size_t)4 * 65536 * 4;
  int* listF = (int*)ws; ws += (size_t)32768 * 4;
  int* counts = (int*)ws; ws += 256;
  int* tm2 = (int*)ws; ws += (size_t)32768 * 4;

  dim3 tb(32, 8);
  hipLaunchKernelGGL(transpose_w_kernel, dim3(8, 8, 4), tb, 0, stream, W_z, Wt_z);
  hipLaunchKernelGGL(transpose_w_kernel, dim3(8, 8, 1), tb, 0, stream, W_z_int, Wt_zint);
  hipLaunchKernelGGL(transpose_w_kernel, dim3(8, 8, 4), tb, 0, stream, W_s, Wt_s);
  hipLaunchKernelGGL(transpose_w_kernel, dim3(8, 8, 1), tb, 0, stream, W_s_int, Wt_sint);
  hipLaunchKernelGGL(transpose_w_kernel, dim3(8, 8, 1), tb, 0, stream, W_p, Wt_p);
  hipLaunchKernelGGL(transpose_w_kernel, dim3(8, 8, 1), tb, 0, stream, W_pf, Wt_pf);

  hipLaunchKernelGGL(gather_x_kernel, dim3(2048), dim3(256), 0, stream,
                     (const float4*)x, initial_map, (float4*)dataA, 65536);

  const int Ms[3] = {65536, 32768, 8192};
  const int Gs[3] = {32768, 8192, 2048};
  float* din = dataA;
  float* outs[3] = {dataB, dataA, (float*)d_out};

  for (int l = 0; l < 3; ++l) {
    int m = Ms[l], g = Gs[l];
    float* pooled = outs[l];
    hipMemsetAsync(pooled, 0, (size_t)g * H * 4, stream);
    hipMemsetAsync(counts, 0, 32, stream);
    hipMemsetAsync(tm2, 0, (size_t)g * 4, stream);

    hipLaunchKernelGGL(bucket_kernel, dim3((m + 255) / 256), dim3(256), 0, stream,
                       tmask[l], pool[l], lists, counts, tm2, m, 65536);

    hipLaunchKernelGGL(type0_kernel, dim3(1024), dim3(256), 0, stream,
                       din, om[l], lists + 0 * 65536, counts + 0, pool[l], pooled, m);

    hipLaunchKernelGGL((tree_gemm<1, false, true, true>), dim3((m + TILE - 1) / TILE),
                       dim3(256), 0, stream, din, om[l], lists + 1 * 65536, counts + 1,
                       pool[l], Wt_p, (const float*)nullptr, pooled, m);

    hipLaunchKernelGGL((tree_gemm<4, true, true, true>), dim3((m + TILE - 1) / TILE),
                       dim3(256), 0, stream, din, om[l], lists + 2 * 65536, counts + 2,
                       pool[l], Wt_z, Wt_zint, pooled, m);

    hipLaunchKernelGGL((tree_gemm<4, true, true, true>), dim3((m + TILE - 1) / TILE),
                       dim3(256), 0, stream, din, om[l], lists + 3 * 65536, counts + 3,
                       pool[l], Wt_s, Wt_sint, pooled, m);

    hipLaunchKernelGGL(elu_bucket_kernel, dim3(g), dim3(256), 0, stream,
                       pooled, tm2, listF, counts + 4, g);

    hipLaunchKernelGGL((tree_gemm<1, false, false, false>), dim3((g + TILE - 1) / TILE),
                       dim3(256), 0, stream, pooled, (const int*)nullptr, listF,
                       counts + 4, (const int*)nullptr, Wt_pf, (const float*)nullptr,
                       pooled, g);

    din = pooled;
  }
}

// Round 2
// 1277.259 us; speedup vs baseline: 2.4565x; 2.4565x over previous
//
#include <hip/hip_runtime.h>
#include <math.h>

#define H 256

typedef __attribute__((ext_vector_type(8))) short bf16x8;
typedef __attribute__((ext_vector_type(4))) float f32x4;
typedef __attribute__((ext_vector_type(4))) short short4v;

__device__ __forceinline__ short f2bf(float f) {
  union { float f; unsigned u; } x;
  x.f = f;
  unsigned r = x.u + 0x7fffu + ((x.u >> 16) & 1u);
  return (short)(r >> 16);
}
__device__ __forceinline__ float bf2f(short s) {
  union { float f; unsigned u; } x;
  x.u = ((unsigned)(unsigned short)s) << 16;
  return x.f;
}

// ---------------- gather + convert: d0bf[i] = bf16(x[map[i]]) ----------------
__global__ __launch_bounds__(256) void gather_cvt_kernel(const float4* __restrict__ x,
                                                         const int* __restrict__ map,
                                                         short4v* __restrict__ out, int n) {
  int total = n * (H / 4);
  for (int idx = blockIdx.x * blockDim.x + threadIdx.x; idx < total;
       idx += gridDim.x * blockDim.x) {
    int e = idx >> 6;
    int q = idx & 63;
    float4 v = x[(size_t)map[e] * 64 + q];
    short4v s;
    s[0] = f2bf(v.x); s[1] = f2bf(v.y); s[2] = f2bf(v.z); s[3] = f2bf(v.w);
    out[idx] = s;
  }
}

// ---------------- convert all 6 weights fp32 -> bf16 (original [o][h] layout) ----
__global__ __launch_bounds__(256) void cvt_w_kernel(const float* __restrict__ s0,
                                                    const float* __restrict__ s1,
                                                    const float* __restrict__ s2,
                                                    const float* __restrict__ s3,
                                                    const float* __restrict__ s4,
                                                    const float* __restrict__ s5,
                                                    short* __restrict__ dst) {
  int i4 = blockIdx.x * blockDim.x + threadIdx.x;
  if (i4 >= 196608) return;
  int e = i4 * 4;
  const float* src;
  int off;
  if (e < 262144)      { src = s0; off = e; }
  else if (e < 327680) { src = s1; off = e - 262144; }
  else if (e < 589824) { src = s2; off = e - 327680; }
  else if (e < 655360) { src = s3; off = e - 589824; }
  else if (e < 720896) { src = s4; off = e - 655360; }
  else                 { src = s5; off = e - 720896; }
  float4 v = *(const float4*)(src + off);
  short4v o;
  o[0] = f2bf(v.x); o[1] = f2bf(v.y); o[2] = f2bf(v.z); o[3] = f2bf(v.w);
  *(short4v*)(dst + e) = o;
}

// ---------------- bucket rows by type + segment-max of tmask ----------------
__global__ __launch_bounds__(256) void bucket_kernel(const int* __restrict__ tmask,
                                                     const int* __restrict__ pool,
                                                     int* __restrict__ lists,
                                                     int* __restrict__ counts,
                                                     int* __restrict__ tm2, int m) {
  int i = blockIdx.x * blockDim.x + threadIdx.x;
  if (i >= m) return;
  int t = tmask[i];
  int p = atomicAdd(&counts[t], 1);
  lists[t * 65536 + p] = i;
  atomicMax(&tm2[pool[i]], t);
}

// ---------------- type 0: pooled[seg] += child0 row ----------------
template <bool BF>
__global__ __launch_bounds__(256) void type0_kernel(const void* __restrict__ data,
                                                    const int* __restrict__ om,
                                                    const int* __restrict__ list,
                                                    const int* __restrict__ cnt,
                                                    const int* __restrict__ pool,
                                                    float* __restrict__ pooled) {
  int n = *cnt;
  int total = n * H;
  for (int idx = blockIdx.x * blockDim.x + threadIdx.x; idx < total;
       idx += gridDim.x * blockDim.x) {
    int e = idx >> 8;
    int o = idx & 255;
    int row = list[e];
    int c = om[row];  // child 0
    if (c >= 0) {
      float v = BF ? bf2f(((const short*)data)[(size_t)c * 256 + o])
                   : ((const float*)data)[(size_t)c * 256 + o];
      atomicAdd(&pooled[(size_t)pool[row] * 256 + o], v);
    }
  }
}

// ---------------- MFMA bucketed gather-GEMM ----------------
// out[i][o] = sum_{k<NCH} sum_h A_k[i][h] * W[k][o][h]
// ASRC: 0 = children via om (A row = list[i]); 1 = dense bf16 temp (A row = i);
//       2 = fp32 rows via list[i] (converted on load)
// OUTM: 0 = atomicAdd into outf[pool[list[i]]]; 1 = bf16 write to outbf[i];
//       2 = overwrite outf[list[i]] fp32 (+ bf16 mirror outbf if non-null)
template <int NCH, int ASRC, int OUTM>
__global__ __launch_bounds__(256) void mfma_gemm(
    const short* __restrict__ Abf, const float* __restrict__ Afp,
    const int* __restrict__ om, int m,
    const int* __restrict__ list, const int* __restrict__ cnt,
    const int* __restrict__ pool, const short* __restrict__ Wbf,
    float* __restrict__ outf, short* __restrict__ outbf, int rowCap) {
  int n = *cnt;
  if (n > rowCap) n = rowCap;
  int rowbase = blockIdx.x * 64;
  if (rowbase >= n) return;
  const int lane = threadIdx.x & 63;
  const int wave = threadIdx.x >> 6;
  const int colbase = wave * 64;
  const int lr = lane & 15;  // frag row (A) / col (B) within 16-tile
  const int kg = lane >> 4;  // k-group (8 contiguous k elems)

  int cidx[4][NCH];
#pragma unroll
  for (int r = 0; r < 4; ++r) {
    int i = rowbase + r * 16 + lr;
    if (i < n) {
      if (ASRC == 0) {
        int row = list[i];
#pragma unroll
        for (int k = 0; k < NCH; ++k) cidx[r][k] = om[k * m + row];
      } else if (ASRC == 1) {
        cidx[r][0] = i;
      } else {
        cidx[r][0] = list[i];
      }
    } else {
#pragma unroll
      for (int k = 0; k < NCH; ++k) cidx[r][k] = -1;
    }
  }

  f32x4 acc[4][4];
#pragma unroll
  for (int r = 0; r < 4; ++r)
#pragma unroll
    for (int c = 0; c < 4; ++c) {
      f32x4 z = {0.f, 0.f, 0.f, 0.f};
      acc[r][c] = z;
    }

#pragma unroll
  for (int kc = 0; kc < NCH; ++kc) {
    int ca[4];
#pragma unroll
    for (int r = 0; r < 4; ++r) ca[r] = cidx[r][kc];
    size_t wbase = ((size_t)(kc * 256 + colbase + lr)) * 256 + kg * 8;
#pragma unroll 2
    for (int ko = 0; ko < 256; ko += 32) {
      bf16x8 a[4], b[4];
#pragma unroll
      for (int r = 0; r < 4; ++r) {
        bf16x8 av = {0, 0, 0, 0, 0, 0, 0, 0};
        if (ca[r] >= 0) {
          if (ASRC == 2) {
            const float* p = Afp + (size_t)ca[r] * 256 + ko + kg * 8;
            float4 u0 = *(const float4*)p;
            float4 u1 = *(const float4*)(p + 4);
            av[0] = f2bf(u0.x); av[1] = f2bf(u0.y); av[2] = f2bf(u0.z); av[3] = f2bf(u0.w);
            av[4] = f2bf(u1.x); av[5] = f2bf(u1.y); av[6] = f2bf(u1.z); av[7] = f2bf(u1.w);
          } else {
            av = *(const bf16x8*)(Abf + (size_t)ca[r] * 256 + ko + kg * 8);
          }
        }
        a[r] = av;
      }
#pragma unroll
      for (int c = 0; c < 4; ++c)
        b[c] = *(const bf16x8*)(Wbf + wbase + (size_t)c * (16 * 256) + ko);
#pragma unroll
      for (int r = 0; r < 4; ++r)
#pragma unroll
        for (int c = 0; c < 4; ++c)
          acc[r][c] =
              __builtin_amdgcn_mfma_f32_16x16x32_bf16(a[r], b[c], acc[r][c], 0, 0, 0);
    }
  }

  // epilogue: D[row=(kg)*4+q][col=lr] per 16x16 tile
#pragma unroll
  for (int r = 0; r < 4; ++r) {
#pragma unroll
    for (int q = 0; q < 4; ++q) {
      int i = rowbase + r * 16 + kg * 4 + q;
      if (i >= n) continue;
      if (OUTM == 0) {
        int seg = pool[list[i]];
        float* dst = outf + (size_t)seg * 256 + colbase + lr;
#pragma unroll
        for (int c = 0; c < 4; ++c) atomicAdd(dst + c * 16, acc[r][c][q]);
      } else if (OUTM == 1) {
        short* dst = outbf + (size_t)i * 256 + colbase + lr;
#pragma unroll
        for (int c = 0; c < 4; ++c) dst[c * 16] = f2bf(acc[r][c][q]);
      } else {
        int c2 = list[i];
        float* df = outf + (size_t)c2 * 256 + colbase + lr;
#pragma unroll
        for (int c = 0; c < 4; ++c) df[c * 16] = acc[r][c][q];
        if (outbf) {
          short* db = outbf + (size_t)c2 * 256 + colbase + lr;
#pragma unroll
          for (int c = 0; c < 4; ++c) db[c * 16] = f2bf(acc[r][c][q]);
        }
      }
    }
  }
}

// ---------------- ELU + bf16 convert + tm2==1 bucket ----------------
__global__ __launch_bounds__(256) void elu_kernel(float* __restrict__ pooled,
                                                  const int* __restrict__ tm2,
                                                  short* __restrict__ nextbf,
                                                  int* __restrict__ listF,
                                                  int* __restrict__ cntF, int g) {
  int s = blockIdx.x;
  if (s >= g) return;
  int t = threadIdx.x;
  int t2 = tm2[s];
  float v = pooled[(size_t)s * 256 + t];
  if (t2 != 0) {
    v = v > 0.f ? v : (expf(v) - 1.f);
    pooled[(size_t)s * 256 + t] = v;
  }
  if (nextbf) nextbf[(size_t)s * 256 + t] = f2bf(v);
  if (t2 == 1 && t == 0) {
    int p = atomicAdd(cntF, 1);
    listF[p] = s;
  }
}

// ---------------- host driver ----------------
extern "C" void kernel_launch(void* const* d_in, const int* in_sizes, int n_in,
                              void* d_out, int out_size, void* d_ws, size_t ws_size,
                              hipStream_t stream) {
  const float* x = (const float*)d_in[0];
  const int* initial_map = (const int*)d_in[1];
  const int* om[3] = {(const int*)d_in[2], (const int*)d_in[5], (const int*)d_in[8]};
  const int* pool[3] = {(const int*)d_in[3], (const int*)d_in[6], (const int*)d_in[9]};
  const int* tmask[3] = {(const int*)d_in[4], (const int*)d_in[7], (const int*)d_in[10]};
  const float* W_z = (const float*)d_in[11];
  const float* W_z_int = (const float*)d_in[12];
  const float* W_s = (const float*)d_in[13];
  const float* W_s_int = (const float*)d_in[14];
  const float* W_p = (const float*)d_in[15];
  const float* W_pf = (const float*)d_in[16];

  char* base = (char*)d_ws;
  short* d0bf = (short*)(base);                       // 32 MB  (65536 x 256 bf16)
  short* reg1 = (short*)(base + 33554432);            // 16 MB  (layer0 temp, then d1bf)
  float* P0   = (float*)(base + 50331648);            // 32 MB  (pooled layer0, fp32)
  short* Wbf  = (short*)(base + 83886080);            // 1.5 MB (all weights bf16)
  int* lists  = (int*)(base + 85458944);              // 1 MB   (4 x 65536)
  int* listF  = (int*)(base + 86507520);              // 128 KB
  int* tm2    = (int*)(base + 86638592);              // 128 KB
  int* counts = (int*)(base + 86769664);              // 256 B
  // aliases into d0bf region (dead after layer 0 GEMMs):
  float* P1    = (float*)(base);                      // 8 MB  (pooled layer1)
  short* temp1 = (short*)(base + 8388608);            // 8 MB  (layer1 temp)
  short* d2bf  = (short*)(base + 16777216);           // 4 MB  (layer2 bf16 input)
  short* temp2 = (short*)(base + 20971520);           // 4 MB  (layer2 temp)

  const short* Wz_bf    = Wbf + 0;
  const short* Wzint_bf = Wbf + 262144;
  const short* Ws_bf    = Wbf + 327680;
  const short* Wsint_bf = Wbf + 589824;
  const short* Wp_bf    = Wbf + 655360;
  const short* Wpf_bf   = Wbf + 720896;

  hipLaunchKernelGGL(cvt_w_kernel, dim3(768), dim3(256), 0, stream, W_z, W_z_int, W_s,
                     W_s_int, W_p, W_pf, Wbf);
  hipLaunchKernelGGL(gather_cvt_kernel, dim3(2048), dim3(256), 0, stream,
                     (const float4*)x, initial_map, (short4v*)d0bf, 65536);

  const int Ms[3] = {65536, 32768, 8192};
  const int Gs[3] = {32768, 8192, 2048};
  const short* dinbf[3] = {d0bf, reg1, d2bf};
  const void* dinT0[3] = {(const void*)d0bf, (const void*)P0, (const void*)P1};
  float* pooledL[3] = {P0, P1, (float*)d_out};
  short* tempb[3] = {reg1, temp1, temp2};
  const int tempCap[3] = {32768, 16384, 8192};
  short* nextbf[3] = {reg1, d2bf, nullptr};

  for (int l = 0; l < 3; ++l) {
    int m = Ms[l], g = Gs[l];
    float* pooled = pooledL[l];
    hipMemsetAsync(pooled, 0, (size_t)g * H * 4, stream);
    hipMemsetAsync(counts, 0, 256, stream);
    hipMemsetAsync(tm2, 0, (size_t)g * 4, stream);

    hipLaunchKernelGGL(bucket_kernel, dim3((m + 255) / 256), dim3(256), 0, stream,
                       tmask[l], pool[l], lists, counts, tm2, m);

    if (l == 0)
      hipLaunchKernelGGL((type0_kernel<true>), dim3(1024), dim3(256), 0, stream,
                         dinT0[l], om[l], lists + 0, counts + 0, pool[l], pooled);
    else
      hipLaunchKernelGGL((type0_kernel<false>), dim3(1024), dim3(256), 0, stream,
                         dinT0[l], om[l], lists + 0, counts + 0, pool[l], pooled);

    int gb = (m + 63) / 64;
    int gt = (tempCap[l] + 63) / 64;

    // type 1: P path (one child through W_p), atomic into pooled
    hipLaunchKernelGGL((mfma_gemm<1, 0, 0>), dim3(gb), dim3(256), 0, stream, dinbf[l],
                       (const float*)nullptr, om[l], m, lists + 1 * 65536, counts + 1,
                       pool[l], Wp_bf, pooled, (short*)nullptr, m);

    // type 2: 4 children through W_z -> temp (bf16), temp through W_z_int -> pooled
    hipLaunchKernelGGL((mfma_gemm<4, 0, 1>), dim3(gb), dim3(256), 0, stream, dinbf[l],
                       (const float*)nullptr, om[l], m, lists + 2 * 65536, counts + 2,
                       (const int*)nullptr, Wz_bf, (float*)nullptr, tempb[l], tempCap[l]);
    hipLaunchKernelGGL((mfma_gemm<1, 1, 0>), dim3(gt), dim3(256), 0, stream, tempb[l],
                       (const float*)nullptr, (const int*)nullptr, m, lists + 2 * 65536,
                       counts + 2, pool[l], Wzint_bf, pooled, (short*)nullptr,
                       tempCap[l]);

    // type 3: same with W_s
    hipLaunchKernelGGL((mfma_gemm<4, 0, 1>), dim3(gb), dim3(256), 0, stream, dinbf[l],
                       (const float*)nullptr, om[l], m, lists + 3 * 65536, counts + 3,
                       (const int*)nullptr, Ws_bf, (float*)nullptr, tempb[l], tempCap[l]);
    hipLaunchKernelGGL((mfma_gemm<1, 1, 0>), dim3(gt), dim3(256), 0, stream, tempb[l],
                       (const float*)nullptr, (const int*)nullptr, m, lists + 3 * 65536,
                       counts + 3, pool[l], Wsint_bf, pooled, (short*)nullptr,
                       tempCap[l]);

    // ELU + bf16 convert for next layer + bucket tm2==1 segments
    hipLaunchKernelGGL(elu_kernel, dim3(g), dim3(256), 0, stream, pooled, tm2, nextbf[l],
                       listF, counts + 4, g);

    // tm2==1 segments: pooled = elu(pooled) @ W_pf^T (in place, fp32 src)
    hipLaunchKernelGGL((mfma_gemm<1, 2, 2>), dim3((g + 63) / 64), dim3(256), 0, stream,
                       (const short*)nullptr, (const float*)pooled, (const int*)nullptr,
                       g, listF, counts + 4, (const int*)nullptr, Wpf_bf, pooled,
                       nextbf[l], g);
  }
}

// Round 3
// 646.840 us; speedup vs baseline: 4.8507x; 1.9746x over previous
//
#include <hip/hip_runtime.h>
#include <math.h>

#define H 256

typedef __attribute__((ext_vector_type(8))) short bf16x8;
typedef __attribute__((ext_vector_type(4))) float f32x4;
typedef __attribute__((ext_vector_type(4))) short short4v;

__device__ __forceinline__ short f2bf(float f) {
  union { float f; unsigned u; } x;
  x.f = f;
  unsigned r = x.u + 0x7fffu + ((x.u >> 16) & 1u);
  return (short)(r >> 16);
}
__device__ __forceinline__ float bf2f(short s) {
  union { float f; unsigned u; } x;
  x.u = ((unsigned)(unsigned short)s) << 16;
  return x.f;
}

// ---------------- gather + convert: d0bf[i] = bf16(x[map[i]]) ----------------
__global__ __launch_bounds__(256) void gather_cvt_kernel(const float4* __restrict__ x,
                                                         const int* __restrict__ map,
                                                         short4v* __restrict__ out, int n) {
  int total = n * (H / 4);
  for (int idx = blockIdx.x * blockDim.x + threadIdx.x; idx < total;
       idx += gridDim.x * blockDim.x) {
    int e = idx >> 6;
    int q = idx & 63;
    float4 v = x[(size_t)map[e] * 64 + q];
    short4v s;
    s[0] = f2bf(v.x); s[1] = f2bf(v.y); s[2] = f2bf(v.z); s[3] = f2bf(v.w);
    out[idx] = s;
  }
}

// ---------------- convert all 6 weights fp32 -> bf16 (original [o][h] layout) ----
__global__ __launch_bounds__(256) void cvt_w_kernel(const float* __restrict__ s0,
                                                    const float* __restrict__ s1,
                                                    const float* __restrict__ s2,
                                                    const float* __restrict__ s3,
                                                    const float* __restrict__ s4,
                                                    const float* __restrict__ s5,
                                                    short* __restrict__ dst) {
  int i4 = blockIdx.x * blockDim.x + threadIdx.x;
  if (i4 >= 196608) return;
  int e = i4 * 4;
  const float* src;
  int off;
  if (e < 262144)      { src = s0; off = e; }
  else if (e < 327680) { src = s1; off = e - 262144; }
  else if (e < 589824) { src = s2; off = e - 327680; }
  else if (e < 655360) { src = s3; off = e - 589824; }
  else if (e < 720896) { src = s4; off = e - 655360; }
  else                 { src = s5; off = e - 720896; }
  float4 v = *(const float4*)(src + off);
  short4v o;
  o[0] = f2bf(v.x); o[1] = f2bf(v.y); o[2] = f2bf(v.z); o[3] = f2bf(v.w);
  *(short4v*)(dst + e) = o;
}

// ---------------- bucket rows by type (LDS-aggregated, low contention) --------
__global__ __launch_bounds__(256) void bucket_kernel(const int* __restrict__ tmask,
                                                     int* __restrict__ lists,
                                                     int* __restrict__ counts, int m) {
  __shared__ int lc[4];
  __shared__ int lbase[4];
  int tid = threadIdx.x;
  if (tid < 4) lc[tid] = 0;
  __syncthreads();
  int i = blockIdx.x * 256 + tid;
  int t = 0, rank = 0;
  bool ok = i < m;
  if (ok) {
    t = tmask[i];
    rank = atomicAdd(&lc[t], 1);
  }
  __syncthreads();
  if (tid < 4) lbase[tid] = atomicAdd(&counts[tid], lc[tid]);
  __syncthreads();
  if (ok) lists[t * 65536 + lbase[t] + rank] = i;
}

// ---------------- per-segment tm2 (contiguous pooling) + listF via ballot -----
__global__ __launch_bounds__(256) void seg_kernel(const int* __restrict__ tmask, int r,
                                                  int g, int* __restrict__ tm2,
                                                  int* __restrict__ listF,
                                                  int* __restrict__ cntF) {
  int s = blockIdx.x * 256 + threadIdx.x;
  if (s >= g) return;  // g is a multiple of 256, so waves stay full
  int t2 = 0;
  for (int j = 0; j < r; ++j) {
    int t = tmask[s * r + j];
    t2 = t > t2 ? t : t2;
  }
  tm2[s] = t2;
  unsigned long long mask = __ballot(t2 == 1);
  if (t2 == 1) {
    int lane = threadIdx.x & 63;
    unsigned long long lt = (lane == 0) ? 0ull : (~0ull >> (64 - lane));
    int rank = __popcll(mask & lt);
    int leader = __ffsll((long long)mask) - 1;
    int base = 0;
    if (lane == leader) base = atomicAdd(cntF, __popcll(mask));
    base = __shfl(base, leader);
    listF[base + rank] = s;
  }
}

// ---------------- type 0: pooled[seg] += child0 row ----------------
template <bool BF>
__global__ __launch_bounds__(256) void type0_kernel(const void* __restrict__ data,
                                                    const int* __restrict__ om,
                                                    const int* __restrict__ list,
                                                    const int* __restrict__ cnt,
                                                    const int* __restrict__ pool,
                                                    float* __restrict__ pooled) {
  int n = *cnt;
  int total = n * H;
  for (int idx = blockIdx.x * blockDim.x + threadIdx.x; idx < total;
       idx += gridDim.x * blockDim.x) {
    int e = idx >> 8;
    int o = idx & 255;
    int row = list[e];
    int c = om[row];  // child 0
    if (c >= 0) {
      float v = BF ? bf2f(((const short*)data)[(size_t)c * 256 + o])
                   : ((const float*)data)[(size_t)c * 256 + o];
      atomicAdd(&pooled[(size_t)pool[row] * 256 + o], v);
    }
  }
}

// ---------------- MFMA bucketed gather-GEMM ----------------
// out[i][o] = sum_{k<NCH} sum_h A_k[i][h] * W[k][o][h]
// ASRC: 0 = children via om (A row = list[i]); 1 = dense bf16 temp (A row = i);
//       2 = fp32 rows via list[i] (converted on load)
// OUTM: 0 = atomicAdd into outf[pool[list[i]]]; 1 = bf16 write to outbf[i];
//       2 = overwrite outf[list[i]] fp32 (+ bf16 mirror outbf if non-null)
template <int NCH, int ASRC, int OUTM>
__global__ __launch_bounds__(256) void mfma_gemm(
    const short* __restrict__ Abf, const float* __restrict__ Afp,
    const int* __restrict__ om, int m,
    const int* __restrict__ list, const int* __restrict__ cnt,
    const int* __restrict__ pool, const short* __restrict__ Wbf,
    float* __restrict__ outf, short* __restrict__ outbf, int rowCap) {
  int n = *cnt;
  if (n > rowCap) n = rowCap;
  int rowbase = blockIdx.x * 64;
  if (rowbase >= n) return;
  const int lane = threadIdx.x & 63;
  const int wave = threadIdx.x >> 6;
  const int colbase = wave * 64;
  const int lr = lane & 15;  // frag row (A) / col (B) within 16-tile
  const int kg = lane >> 4;  // k-group (8 contiguous k elems)

  int cidx[4][NCH];
#pragma unroll
  for (int r = 0; r < 4; ++r) {
    int i = rowbase + r * 16 + lr;
    if (i < n) {
      if (ASRC == 0) {
        int row = list[i];
#pragma unroll
        for (int k = 0; k < NCH; ++k) cidx[r][k] = om[k * m + row];
      } else if (ASRC == 1) {
        cidx[r][0] = i;
      } else {
        cidx[r][0] = list[i];
      }
    } else {
#pragma unroll
      for (int k = 0; k < NCH; ++k) cidx[r][k] = -1;
    }
  }

  f32x4 acc[4][4];
#pragma unroll
  for (int r = 0; r < 4; ++r)
#pragma unroll
    for (int c = 0; c < 4; ++c) {
      f32x4 z = {0.f, 0.f, 0.f, 0.f};
      acc[r][c] = z;
    }

#pragma unroll
  for (int kc = 0; kc < NCH; ++kc) {
    int ca[4];
#pragma unroll
    for (int r = 0; r < 4; ++r) ca[r] = cidx[r][kc];
    size_t wbase = ((size_t)(kc * 256 + colbase + lr)) * 256 + kg * 8;
#pragma unroll 2
    for (int ko = 0; ko < 256; ko += 32) {
      bf16x8 a[4], b[4];
#pragma unroll
      for (int r = 0; r < 4; ++r) {
        bf16x8 av = {0, 0, 0, 0, 0, 0, 0, 0};
        if (ca[r] >= 0) {
          if (ASRC == 2) {
            const float* p = Afp + (size_t)ca[r] * 256 + ko + kg * 8;
            float4 u0 = *(const float4*)p;
            float4 u1 = *(const float4*)(p + 4);
            av[0] = f2bf(u0.x); av[1] = f2bf(u0.y); av[2] = f2bf(u0.z); av[3] = f2bf(u0.w);
            av[4] = f2bf(u1.x); av[5] = f2bf(u1.y); av[6] = f2bf(u1.z); av[7] = f2bf(u1.w);
          } else {
            av = *(const bf16x8*)(Abf + (size_t)ca[r] * 256 + ko + kg * 8);
          }
        }
        a[r] = av;
      }
#pragma unroll
      for (int c = 0; c < 4; ++c)
        b[c] = *(const bf16x8*)(Wbf + wbase + (size_t)c * (16 * 256) + ko);
#pragma unroll
      for (int r = 0; r < 4; ++r)
#pragma unroll
        for (int c = 0; c < 4; ++c)
          acc[r][c] =
              __builtin_amdgcn_mfma_f32_16x16x32_bf16(a[r], b[c], acc[r][c], 0, 0, 0);
    }
  }

  // epilogue: D[row=(kg)*4+q][col=lr] per 16x16 tile
#pragma unroll
  for (int r = 0; r < 4; ++r) {
#pragma unroll
    for (int q = 0; q < 4; ++q) {
      int i = rowbase + r * 16 + kg * 4 + q;
      if (i >= n) continue;
      if (OUTM == 0) {
        int seg = pool[list[i]];
        float* dst = outf + (size_t)seg * 256 + colbase + lr;
#pragma unroll
        for (int c = 0; c < 4; ++c) atomicAdd(dst + c * 16, acc[r][c][q]);
      } else if (OUTM == 1) {
        short* dst = outbf + (size_t)i * 256 + colbase + lr;
#pragma unroll
        for (int c = 0; c < 4; ++c) dst[c * 16] = f2bf(acc[r][c][q]);
      } else {
        int c2 = list[i];
        float* df = outf + (size_t)c2 * 256 + colbase + lr;
#pragma unroll
        for (int c = 0; c < 4; ++c) df[c * 16] = acc[r][c][q];
        if (outbf) {
          short* db = outbf + (size_t)c2 * 256 + colbase + lr;
#pragma unroll
          for (int c = 0; c < 4; ++c) db[c * 16] = f2bf(acc[r][c][q]);
        }
      }
    }
  }
}

// ---------------- ELU + bf16 convert (tm2 precomputed) ----------------
__global__ __launch_bounds__(256) void elu_kernel(float* __restrict__ pooled,
                                                  const int* __restrict__ tm2,
                                                  short* __restrict__ nextbf, int g) {
  int s = blockIdx.x;
  if (s >= g) return;
  int t = threadIdx.x;
  int t2 = tm2[s];
  float v = pooled[(size_t)s * 256 + t];
  if (t2 != 0) {
    v = v > 0.f ? v : (expf(v) - 1.f);
    pooled[(size_t)s * 256 + t] = v;
  }
  if (nextbf) nextbf[(size_t)s * 256 + t] = f2bf(v);
}

// ---------------- host driver ----------------
extern "C" void kernel_launch(void* const* d_in, const int* in_sizes, int n_in,
                              void* d_out, int out_size, void* d_ws, size_t ws_size,
                              hipStream_t stream) {
  const float* x = (const float*)d_in[0];
  const int* initial_map = (const int*)d_in[1];
  const int* om[3] = {(const int*)d_in[2], (const int*)d_in[5], (const int*)d_in[8]};
  const int* pool[3] = {(const int*)d_in[3], (const int*)d_in[6], (const int*)d_in[9]};
  const int* tmask[3] = {(const int*)d_in[4], (const int*)d_in[7], (const int*)d_in[10]};
  const float* W_z = (const float*)d_in[11];
  const float* W_z_int = (const float*)d_in[12];
  const float* W_s = (const float*)d_in[13];
  const float* W_s_int = (const float*)d_in[14];
  const float* W_p = (const float*)d_in[15];
  const float* W_pf = (const float*)d_in[16];

  char* base = (char*)d_ws;
  short* d0bf = (short*)(base);                       // 32 MB  (65536 x 256 bf16)
  short* reg1 = (short*)(base + 33554432);            // 16 MB  (layer0 temp, then d1bf)
  float* P0   = (float*)(base + 50331648);            // 32 MB  (pooled layer0, fp32)
  short* Wbf  = (short*)(base + 83886080);            // 1.5 MB (all weights bf16)
  int* lists  = (int*)(base + 85458944);              // 1 MB   (4 x 65536)
  int* listF  = (int*)(base + 86507520);              // 128 KB
  int* tm2    = (int*)(base + 86638592);              // 128 KB
  int* counts = (int*)(base + 86769664);              // 256 B
  // aliases into d0bf region (dead after layer 0 GEMMs):
  float* P1    = (float*)(base);                      // 8 MB  (pooled layer1)
  short* temp1 = (short*)(base + 8388608);            // 8 MB  (layer1 temp)
  short* d2bf  = (short*)(base + 16777216);           // 4 MB  (layer2 bf16 input)
  short* temp2 = (short*)(base + 20971520);           // 4 MB  (layer2 temp)

  const short* Wz_bf    = Wbf + 0;
  const short* Wzint_bf = Wbf + 262144;
  const short* Ws_bf    = Wbf + 327680;
  const short* Wsint_bf = Wbf + 589824;
  const short* Wp_bf    = Wbf + 655360;
  const short* Wpf_bf   = Wbf + 720896;

  hipLaunchKernelGGL(cvt_w_kernel, dim3(768), dim3(256), 0, stream, W_z, W_z_int, W_s,
                     W_s_int, W_p, W_pf, Wbf);
  hipLaunchKernelGGL(gather_cvt_kernel, dim3(2048), dim3(256), 0, stream,
                     (const float4*)x, initial_map, (short4v*)d0bf, 65536);

  const int Ms[3] = {65536, 32768, 8192};
  const int Gs[3] = {32768, 8192, 2048};
  const short* dinbf[3] = {d0bf, reg1, d2bf};
  const void* dinT0[3] = {(const void*)d0bf, (const void*)P0, (const void*)P1};
  float* pooledL[3] = {P0, P1, (float*)d_out};
  short* tempb[3] = {reg1, temp1, temp2};
  const int tempCap[3] = {32768, 16384, 8192};
  short* nextbf[3] = {reg1, d2bf, nullptr};

  for (int l = 0; l < 3; ++l) {
    int m = Ms[l], g = Gs[l];
    float* pooled = pooledL[l];
    hipMemsetAsync(pooled, 0, (size_t)g * H * 4, stream);
    hipMemsetAsync(counts, 0, 256, stream);

    hipLaunchKernelGGL(bucket_kernel, dim3((m + 255) / 256), dim3(256), 0, stream,
                       tmask[l], lists, counts, m);

    hipLaunchKernelGGL(seg_kernel, dim3(g / 256), dim3(256), 0, stream, tmask[l], m / g,
                       g, tm2, listF, counts + 4);

    if (l == 0)
      hipLaunchKernelGGL((type0_kernel<true>), dim3(1024), dim3(256), 0, stream,
                         dinT0[l], om[l], lists + 0, counts + 0, pool[l], pooled);
    else
      hipLaunchKernelGGL((type0_kernel<false>), dim3(1024), dim3(256), 0, stream,
                         dinT0[l], om[l], lists + 0, counts + 0, pool[l], pooled);

    int gb = (m + 63) / 64;
    int gt = (tempCap[l] + 63) / 64;

    // type 1: P path (one child through W_p), atomic into pooled
    hipLaunchKernelGGL((mfma_gemm<1, 0, 0>), dim3(gb), dim3(256), 0, stream, dinbf[l],
                       (const float*)nullptr, om[l], m, lists + 1 * 65536, counts + 1,
                       pool[l], Wp_bf, pooled, (short*)nullptr, m);

    // type 2: 4 children through W_z -> temp (bf16), temp through W_z_int -> pooled
    hipLaunchKernelGGL((mfma_gemm<4, 0, 1>), dim3(gb), dim3(256), 0, stream, dinbf[l],
                       (const float*)nullptr, om[l], m, lists + 2 * 65536, counts + 2,
                       (const int*)nullptr, Wz_bf, (float*)nullptr, tempb[l], tempCap[l]);
    hipLaunchKernelGGL((mfma_gemm<1, 1, 0>), dim3(gt), dim3(256), 0, stream, tempb[l],
                       (const float*)nullptr, (const int*)nullptr, m, lists + 2 * 65536,
                       counts + 2, pool[l], Wzint_bf, pooled, (short*)nullptr,
                       tempCap[l]);

    // type 3: same with W_s
    hipLaunchKernelGGL((mfma_gemm<4, 0, 1>), dim3(gb), dim3(256), 0, stream, dinbf[l],
                       (const float*)nullptr, om[l], m, lists + 3 * 65536, counts + 3,
                       (const int*)nullptr, Ws_bf, (float*)nullptr, tempb[l], tempCap[l]);
    hipLaunchKernelGGL((mfma_gemm<1, 1, 0>), dim3(gt), dim3(256), 0, stream, tempb[l],
                       (const float*)nullptr, (const int*)nullptr, m, lists + 3 * 65536,
                       counts + 3, pool[l], Wsint_bf, pooled, (short*)nullptr,
                       tempCap[l]);

    // ELU + bf16 convert for next layer
    hipLaunchKernelGGL(elu_kernel, dim3(g), dim3(256), 0, stream, pooled, tm2,
                       nextbf[l], g);

    // tm2==1 segments: pooled = elu(pooled) @ W_pf^T (in place, fp32 src)
    hipLaunchKernelGGL((mfma_gemm<1, 2, 2>), dim3((g + 63) / 64), dim3(256), 0, stream,
                       (const short*)nullptr, (const float*)pooled, (const int*)nullptr,
                       g, listF, counts + 4, (const int*)nullptr, Wpf_bf, pooled,
                       nextbf[l], g);
  }
}

// Round 4
// 446.270 us; speedup vs baseline: 7.0308x; 1.4494x over previous
//
#include <hip/hip_runtime.h>
#include <math.h>

#define H 256

typedef __attribute__((ext_vector_type(8))) short bf16x8;
typedef __attribute__((ext_vector_type(4))) float f32x4;
typedef __attribute__((ext_vector_type(4))) short short4v;

__device__ __forceinline__ short f2bf(float f) {
  union { float f; unsigned u; } x;
  x.f = f;
  unsigned r = x.u + 0x7fffu + ((x.u >> 16) & 1u);
  return (short)(r >> 16);
}
__device__ __forceinline__ float bf2f(short s) {
  union { float f; unsigned u; } x;
  x.u = ((unsigned)(unsigned short)s) << 16;
  return x.f;
}

// ---------------- gather + convert: d0bf[i] = bf16(x[map[i]]) ----------------
__global__ __launch_bounds__(256) void gather_cvt_kernel(const float4* __restrict__ x,
                                                         const int* __restrict__ map,
                                                         short4v* __restrict__ out, int n) {
  int total = n * (H / 4);
  for (int idx = blockIdx.x * blockDim.x + threadIdx.x; idx < total;
       idx += gridDim.x * blockDim.x) {
    int e = idx >> 6;
    int q = idx & 63;
    float4 v = x[(size_t)map[e] * 64 + q];
    short4v s;
    s[0] = f2bf(v.x); s[1] = f2bf(v.y); s[2] = f2bf(v.z); s[3] = f2bf(v.w);
    out[idx] = s;
  }
}

// ---------------- convert all 6 weights fp32 -> bf16 (original [o][h] layout) ----
__global__ __launch_bounds__(256) void cvt_w_kernel(const float* __restrict__ s0,
                                                    const float* __restrict__ s1,
                                                    const float* __restrict__ s2,
                                                    const float* __restrict__ s3,
                                                    const float* __restrict__ s4,
                                                    const float* __restrict__ s5,
                                                    short* __restrict__ dst) {
  int i4 = blockIdx.x * blockDim.x + threadIdx.x;
  if (i4 >= 196608) return;
  int e = i4 * 4;
  const float* src;
  int off;
  if (e < 262144)      { src = s0; off = e; }
  else if (e < 327680) { src = s1; off = e - 262144; }
  else if (e < 589824) { src = s2; off = e - 327680; }
  else if (e < 655360) { src = s3; off = e - 589824; }
  else if (e < 720896) { src = s4; off = e - 655360; }
  else                 { src = s5; off = e - 720896; }
  float4 v = *(const float4*)(src + off);
  short4v o;
  o[0] = f2bf(v.x); o[1] = f2bf(v.y); o[2] = f2bf(v.z); o[3] = f2bf(v.w);
  *(short4v*)(dst + e) = o;
}

// ------- bucket rows by type (LDS-aggregated) + per-segment tm2 + listF -------
__global__ __launch_bounds__(256) void bucket_seg_kernel(const int* __restrict__ tmask,
                                                         int r, int g,
                                                         int* __restrict__ lists,
                                                         int* __restrict__ counts,
                                                         int* __restrict__ tm2,
                                                         int* __restrict__ listF,
                                                         int* __restrict__ cntF, int m) {
  __shared__ int lc[4];
  __shared__ int lbase[4];
  int tid = threadIdx.x;
  if (tid < 4) lc[tid] = 0;
  __syncthreads();
  int i = blockIdx.x * 256 + tid;
  int t = 0, rank = 0;
  bool ok = i < m;
  if (ok) {
    t = tmask[i];
    rank = atomicAdd(&lc[t], 1);
  }
  __syncthreads();
  if (tid < 4) lbase[tid] = atomicAdd(&counts[tid], lc[tid]);
  __syncthreads();
  if (ok) lists[t * 65536 + lbase[t] + rank] = i;

  // segment work: ids < g (g is a multiple of 256 -> full waves)
  int s = i;
  if (s < g) {
    int t2 = 0;
    for (int j = 0; j < r; ++j) {
      int tt = tmask[s * r + j];
      t2 = tt > t2 ? tt : t2;
    }
    tm2[s] = t2;
    unsigned long long mask = __ballot(t2 == 1);
    if (t2 == 1) {
      int lane = tid & 63;
      unsigned long long lt = (lane == 0) ? 0ull : (~0ull >> (64 - lane));
      int rnk = __popcll(mask & lt);
      int leader = __ffsll((long long)mask) - 1;
      int base = 0;
      if (lane == leader) base = atomicAdd(cntF, __popcll(mask));
      base = __shfl(base, leader);
      listF[base + rnk] = s;
    }
  }
}

// ---------------- fused per-layer GEMM: all 4 type paths in one launch --------
// grid = 4*nb, nb = m/32. block range [0,nb): type1, [nb,2nb): type2,
// [2nb,3nb): type3, [3nb,4nb): type0 (plain pooled += child0).
__global__ __launch_bounds__(256) void fused_gemm(
    const short* __restrict__ Abf, const float* __restrict__ Aprev,
    const int* __restrict__ om, int m,
    const int* __restrict__ lists, const int* __restrict__ counts,
    const int* __restrict__ pool,
    const short* __restrict__ Wp,
    const short* __restrict__ Wz, const short* __restrict__ Wzint,
    const short* __restrict__ Ws, const short* __restrict__ Wsint,
    float* __restrict__ pooled, int nb, int isL0) {
  int bt = (int)blockIdx.x / nb;        // 0..3
  int bi = (int)blockIdx.x % nb;
  int type = (bt == 3) ? 0 : (bt + 1);
  int n = counts[type];
  int rowbase = bi * 32;
  if (rowbase >= n) return;
  const int* list = lists + type * 65536;
  const int tid = threadIdx.x;

  if (type == 0) {
    // pooled[pool[row]] += child0 row (bf16 src at layer 0, fp32 after)
    int lim = n - rowbase;
    if (lim > 32) lim = 32;
    for (int idx = tid; idx < lim * 256; idx += 256) {
      int e = rowbase + (idx >> 8);
      int o = idx & 255;
      int row = list[e];
      int c = om[row];
      if (c >= 0) {
        float v = isL0 ? bf2f(Abf[(size_t)c * 256 + o])
                       : Aprev[(size_t)c * 256 + o];
        atomicAdd(&pooled[(size_t)pool[row] * 256 + o], v);
      }
    }
    return;
  }

  const int lane = tid & 63;
  const int wave = tid >> 6;
  const int colbase = wave * 64;
  const int lr = lane & 15;
  const int kg = lane >> 4;

  __shared__ __align__(16) short temp[32 * 256];  // 16 KB, XOR-swizzled

  f32x4 acc[2][4];
#pragma unroll
  for (int rt = 0; rt < 2; ++rt)
#pragma unroll
    for (int c = 0; c < 4; ++c) {
      f32x4 z = {0.f, 0.f, 0.f, 0.f};
      acc[rt][c] = z;
    }

  if (type == 1) {
    int src[2];
#pragma unroll
    for (int rt = 0; rt < 2; ++rt) {
      int i = rowbase + rt * 16 + lr;
      src[rt] = (i < n) ? om[list[i]] : -1;   // child 0
    }
#pragma unroll 2
    for (int ko = 0; ko < 256; ko += 32) {
      bf16x8 b[4];
#pragma unroll
      for (int c = 0; c < 4; ++c)
        b[c] = *(const bf16x8*)(Wp + (size_t)(colbase + c * 16 + lr) * 256 + ko + kg * 8);
#pragma unroll
      for (int rt = 0; rt < 2; ++rt) {
        bf16x8 a = {0, 0, 0, 0, 0, 0, 0, 0};
        if (src[rt] >= 0)
          a = *(const bf16x8*)(Abf + (size_t)src[rt] * 256 + ko + kg * 8);
#pragma unroll
        for (int c = 0; c < 4; ++c)
          acc[rt][c] = __builtin_amdgcn_mfma_f32_16x16x32_bf16(a, b[c], acc[rt][c], 0, 0, 0);
      }
    }
  } else {
    const short* W1 = (type == 2) ? Wz : Ws;
    const short* W2 = (type == 2) ? Wzint : Wsint;
    int cidx[2][4];
#pragma unroll
    for (int rt = 0; rt < 2; ++rt) {
      int i = rowbase + rt * 16 + lr;
      int row = (i < n) ? list[i] : -1;
#pragma unroll
      for (int k = 0; k < 4; ++k) cidx[rt][k] = (row >= 0) ? om[k * m + row] : -1;
    }
#pragma unroll
    for (int kc = 0; kc < 4; ++kc) {
      const short* W1k = W1 + (size_t)kc * 65536;
#pragma unroll 2
      for (int ko = 0; ko < 256; ko += 32) {
        bf16x8 b[4];
#pragma unroll
        for (int c = 0; c < 4; ++c)
          b[c] = *(const bf16x8*)(W1k + (size_t)(colbase + c * 16 + lr) * 256 + ko + kg * 8);
#pragma unroll
        for (int rt = 0; rt < 2; ++rt) {
          bf16x8 a = {0, 0, 0, 0, 0, 0, 0, 0};
          int ca = cidx[rt][kc];
          if (ca >= 0)
            a = *(const bf16x8*)(Abf + (size_t)ca * 256 + ko + kg * 8);
#pragma unroll
          for (int c = 0; c < 4; ++c)
            acc[rt][c] = __builtin_amdgcn_mfma_f32_16x16x32_bf16(a, b[c], acc[rt][c], 0, 0, 0);
        }
      }
    }
    // temp tile -> LDS (bf16), XOR-swizzled so GEMM2's row-reads are conflict-free
#pragma unroll
    for (int rt = 0; rt < 2; ++rt)
#pragma unroll
      for (int c = 0; c < 4; ++c) {
        int col = colbase + c * 16 + lr;
#pragma unroll
        for (int q = 0; q < 4; ++q) {
          int row = rt * 16 + kg * 4 + q;
          int off = (row * 512 + col * 2) ^ ((row & 7) << 4);
          *(short*)((char*)temp + off) = f2bf(acc[rt][c][q]);
        }
      }
    __syncthreads();
#pragma unroll
    for (int rt = 0; rt < 2; ++rt)
#pragma unroll
      for (int c = 0; c < 4; ++c) {
        f32x4 z = {0.f, 0.f, 0.f, 0.f};
        acc[rt][c] = z;
      }
#pragma unroll 2
    for (int ko = 0; ko < 256; ko += 32) {
      bf16x8 b[4];
#pragma unroll
      for (int c = 0; c < 4; ++c)
        b[c] = *(const bf16x8*)(W2 + (size_t)(colbase + c * 16 + lr) * 256 + ko + kg * 8);
#pragma unroll
      for (int rt = 0; rt < 2; ++rt) {
        int row = rt * 16 + lr;
        int off = (row * 512 + (ko + kg * 8) * 2) ^ ((row & 7) << 4);
        bf16x8 a = *(const bf16x8*)((char*)temp + off);
#pragma unroll
        for (int c = 0; c < 4; ++c)
          acc[rt][c] = __builtin_amdgcn_mfma_f32_16x16x32_bf16(a, b[c], acc[rt][c], 0, 0, 0);
      }
    }
  }

  // epilogue: atomicAdd into pooled[pool[list[i]]]
#pragma unroll
  for (int rt = 0; rt < 2; ++rt) {
#pragma unroll
    for (int q = 0; q < 4; ++q) {
      int i2 = rowbase + rt * 16 + kg * 4 + q;
      if (i2 >= n) continue;
      int seg = pool[list[i2]];
      float* dst = pooled + (size_t)seg * 256 + colbase + lr;
#pragma unroll
      for (int c = 0; c < 4; ++c) atomicAdd(dst + c * 16, acc[rt][c][q]);
    }
  }
}

// ---------------- ELU + bf16 convert (tm2 precomputed) ----------------
__global__ __launch_bounds__(256) void elu_kernel(float* __restrict__ pooled,
                                                  const int* __restrict__ tm2,
                                                  short* __restrict__ nextbf, int g) {
  int s = blockIdx.x;
  if (s >= g) return;
  int t = threadIdx.x;
  int t2 = tm2[s];
  float v = pooled[(size_t)s * 256 + t];
  if (t2 != 0) {
    v = v > 0.f ? v : (expf(v) - 1.f);
    pooled[(size_t)s * 256 + t] = v;
  }
  if (nextbf) nextbf[(size_t)s * 256 + t] = f2bf(v);
}

// -------- tm2==1 segments: rows = rows @ W_pf^T in place (fp32 src) ----------
__global__ __launch_bounds__(256) void pf_gemm(const float* __restrict__ Afp,
                                               const int* __restrict__ listF,
                                               const int* __restrict__ cnt,
                                               const short* __restrict__ Wpf,
                                               float* __restrict__ outf,
                                               short* __restrict__ outbf) {
  int n = *cnt;
  int rowbase = blockIdx.x * 32;
  if (rowbase >= n) return;
  const int lane = threadIdx.x & 63;
  const int wave = threadIdx.x >> 6;
  const int colbase = wave * 64;
  const int lr = lane & 15;
  const int kg = lane >> 4;

  int src[2];
#pragma unroll
  for (int rt = 0; rt < 2; ++rt) {
    int i = rowbase + rt * 16 + lr;
    src[rt] = (i < n) ? listF[i] : -1;
  }

  f32x4 acc[2][4];
#pragma unroll
  for (int rt = 0; rt < 2; ++rt)
#pragma unroll
    for (int c = 0; c < 4; ++c) {
      f32x4 z = {0.f, 0.f, 0.f, 0.f};
      acc[rt][c] = z;
    }

#pragma unroll 2
  for (int ko = 0; ko < 256; ko += 32) {
    bf16x8 b[4];
#pragma unroll
    for (int c = 0; c < 4; ++c)
      b[c] = *(const bf16x8*)(Wpf + (size_t)(colbase + c * 16 + lr) * 256 + ko + kg * 8);
#pragma unroll
    for (int rt = 0; rt < 2; ++rt) {
      bf16x8 a = {0, 0, 0, 0, 0, 0, 0, 0};
      if (src[rt] >= 0) {
        const float* p = Afp + (size_t)src[rt] * 256 + ko + kg * 8;
        float4 u0 = *(const float4*)p;
        float4 u1 = *(const float4*)(p + 4);
        a[0] = f2bf(u0.x); a[1] = f2bf(u0.y); a[2] = f2bf(u0.z); a[3] = f2bf(u0.w);
        a[4] = f2bf(u1.x); a[5] = f2bf(u1.y); a[6] = f2bf(u1.z); a[7] = f2bf(u1.w);
      }
#pragma unroll
      for (int c = 0; c < 4; ++c)
        acc[rt][c] = __builtin_amdgcn_mfma_f32_16x16x32_bf16(a, b[c], acc[rt][c], 0, 0, 0);
    }
  }

  __syncthreads();  // all waves done READING these rows before any wave overwrites

#pragma unroll
  for (int rt = 0; rt < 2; ++rt) {
#pragma unroll
    for (int q = 0; q < 4; ++q) {
      int i2 = rowbase + rt * 16 + kg * 4 + q;
      if (i2 >= n) continue;
      int c2 = listF[i2];
      float* df = outf + (size_t)c2 * 256 + colbase + lr;
#pragma unroll
      for (int c = 0; c < 4; ++c) df[c * 16] = acc[rt][c][q];
      if (outbf) {
        short* db = outbf + (size_t)c2 * 256 + colbase + lr;
#pragma unroll
        for (int c = 0; c < 4; ++c) db[c * 16] = f2bf(acc[rt][c][q]);
      }
    }
  }
}

// ---------------- host driver ----------------
extern "C" void kernel_launch(void* const* d_in, const int* in_sizes, int n_in,
                              void* d_out, int out_size, void* d_ws, size_t ws_size,
                              hipStream_t stream) {
  const float* x = (const float*)d_in[0];
  const int* initial_map = (const int*)d_in[1];
  const int* om[3] = {(const int*)d_in[2], (const int*)d_in[5], (const int*)d_in[8]};
  const int* pool[3] = {(const int*)d_in[3], (const int*)d_in[6], (const int*)d_in[9]};
  const int* tmask[3] = {(const int*)d_in[4], (const int*)d_in[7], (const int*)d_in[10]};
  const float* W_z = (const float*)d_in[11];
  const float* W_z_int = (const float*)d_in[12];
  const float* W_s = (const float*)d_in[13];
  const float* W_s_int = (const float*)d_in[14];
  const float* W_p = (const float*)d_in[15];
  const float* W_pf = (const float*)d_in[16];

  char* base = (char*)d_ws;
  short* d0bf = (short*)(base);                       // 32 MB (65536 x 256 bf16)
  short* d1bf = (short*)(base + 33554432);            // 16 MB (layer1 bf16 input)
  float* P0   = (float*)(base + 50331648);            // 32 MB (pooled layer0 fp32)
  short* Wbf  = (short*)(base + 83886080);            // 1.5 MB (weights bf16)
  int* lists  = (int*)(base + 85458944);              // 1 MB (4 x 65536)
  int* listF  = (int*)(base + 86507520);              // 128 KB
  int* tm2    = (int*)(base + 86638592);              // 128 KB
  int* counts = (int*)(base + 86769664);              // 256 B
  // aliases into d0bf region (dead after layer 0 GEMMs):
  float* P1   = (float*)(base);                       // 8 MB (pooled layer1)
  short* d2bf = (short*)(base + 16777216);            // 4 MB (layer2 bf16 input)

  const short* Wz_bf    = Wbf + 0;
  const short* Wzint_bf = Wbf + 262144;
  const short* Ws_bf    = Wbf + 327680;
  const short* Wsint_bf = Wbf + 589824;
  const short* Wp_bf    = Wbf + 655360;
  const short* Wpf_bf   = Wbf + 720896;

  hipLaunchKernelGGL(cvt_w_kernel, dim3(768), dim3(256), 0, stream, W_z, W_z_int, W_s,
                     W_s_int, W_p, W_pf, Wbf);
  hipLaunchKernelGGL(gather_cvt_kernel, dim3(2048), dim3(256), 0, stream,
                     (const float4*)x, initial_map, (short4v*)d0bf, 65536);

  const int Ms[3] = {65536, 32768, 8192};
  const int Gs[3] = {32768, 8192, 2048};
  const short* dinbf[3] = {d0bf, d1bf, d2bf};
  const float* dinfp[3] = {nullptr, P0, P1};
  float* pooledL[3] = {P0, P1, (float*)d_out};
  short* nextbf[3] = {d1bf, d2bf, nullptr};

  for (int l = 0; l < 3; ++l) {
    int m = Ms[l], g = Gs[l];
    float* pooled = pooledL[l];
    hipMemsetAsync(pooled, 0, (size_t)g * H * 4, stream);
    hipMemsetAsync(counts, 0, 256, stream);

    hipLaunchKernelGGL(bucket_seg_kernel, dim3(m / 256), dim3(256), 0, stream,
                       tmask[l], m / g, g, lists, counts, tm2, listF, counts + 4, m);

    int nb = m / 32;
    hipLaunchKernelGGL(fused_gemm, dim3(4 * nb), dim3(256), 0, stream, dinbf[l],
                       dinfp[l], om[l], m, lists, counts, pool[l], Wp_bf, Wz_bf,
                       Wzint_bf, Ws_bf, Wsint_bf, pooled, nb, l == 0 ? 1 : 0);

    hipLaunchKernelGGL(elu_kernel, dim3(g), dim3(256), 0, stream, pooled, tm2,
                       nextbf[l], g);

    hipLaunchKernelGGL(pf_gemm, dim3(g / 32), dim3(256), 0, stream, pooled, listF,
                       counts + 4, Wpf_bf, pooled, nextbf[l]);
  }
}

// Round 5
// 389.542 us; speedup vs baseline: 8.0546x; 1.1456x over previous
//
#include <hip/hip_runtime.h>
#include <math.h>

#define H 256

typedef __attribute__((ext_vector_type(8))) short bf16x8;
typedef __attribute__((ext_vector_type(4))) float f32x4;
typedef __attribute__((ext_vector_type(4))) short short4v;

__device__ __forceinline__ short f2bf(float f) {
  union { float f; unsigned u; } x;
  x.f = f;
  unsigned r = x.u + 0x7fffu + ((x.u >> 16) & 1u);
  return (short)(r >> 16);
}
__device__ __forceinline__ float bf2f(short s) {
  union { float f; unsigned u; } x;
  x.u = ((unsigned)(unsigned short)s) << 16;
  return x.f;
}

// ---------------- gather + convert: d0bf[i] = bf16(x[map[i]]) ----------------
__global__ __launch_bounds__(256) void gather_cvt_kernel(const float4* __restrict__ x,
                                                         const int* __restrict__ map,
                                                         short4v* __restrict__ out, int n) {
  int total = n * (H / 4);
  for (int idx = blockIdx.x * blockDim.x + threadIdx.x; idx < total;
       idx += gridDim.x * blockDim.x) {
    int e = idx >> 6;
    int q = idx & 63;
    float4 v = x[(size_t)map[e] * 64 + q];
    short4v s;
    s[0] = f2bf(v.x); s[1] = f2bf(v.y); s[2] = f2bf(v.z); s[3] = f2bf(v.w);
    out[idx] = s;
  }
}

// ---------------- convert all 6 weights fp32 -> bf16 (original [o][h] layout) ----
__global__ __launch_bounds__(256) void cvt_w_kernel(const float* __restrict__ s0,
                                                    const float* __restrict__ s1,
                                                    const float* __restrict__ s2,
                                                    const float* __restrict__ s3,
                                                    const float* __restrict__ s4,
                                                    const float* __restrict__ s5,
                                                    short* __restrict__ dst) {
  int i4 = blockIdx.x * blockDim.x + threadIdx.x;
  if (i4 >= 196608) return;
  int e = i4 * 4;
  const float* src;
  int off;
  if (e < 262144)      { src = s0; off = e; }
  else if (e < 327680) { src = s1; off = e - 262144; }
  else if (e < 589824) { src = s2; off = e - 327680; }
  else if (e < 655360) { src = s3; off = e - 589824; }
  else if (e < 720896) { src = s4; off = e - 655360; }
  else                 { src = s5; off = e - 720896; }
  float4 v = *(const float4*)(src + off);
  short4v o;
  o[0] = f2bf(v.x); o[1] = f2bf(v.y); o[2] = f2bf(v.z); o[3] = f2bf(v.w);
  *(short4v*)(dst + e) = o;
}

// ------- bucket rows by type (LDS-aggregated) + per-segment tm2 + listF -------
__global__ __launch_bounds__(256) void bucket_seg_kernel(const int* __restrict__ tmask,
                                                         int r, int g,
                                                         int* __restrict__ lists,
                                                         int* __restrict__ counts,
                                                         int* __restrict__ tm2,
                                                         int* __restrict__ listF,
                                                         int* __restrict__ cntF, int m) {
  __shared__ int lc[4];
  __shared__ int lbase[4];
  int tid = threadIdx.x;
  if (tid < 4) lc[tid] = 0;
  __syncthreads();
  int i = blockIdx.x * 256 + tid;
  int t = 0, rank = 0;
  bool ok = i < m;
  if (ok) {
    t = tmask[i];
    rank = atomicAdd(&lc[t], 1);
  }
  __syncthreads();
  if (tid < 4) lbase[tid] = atomicAdd(&counts[tid], lc[tid]);
  __syncthreads();
  if (ok) lists[t * 65536 + lbase[t] + rank] = i;

  // segment work: ids < g (g is a multiple of 256 -> full waves)
  int s = i;
  if (s < g) {
    int t2 = 0;
    for (int j = 0; j < r; ++j) {
      int tt = tmask[s * r + j];
      t2 = tt > t2 ? tt : t2;
    }
    tm2[s] = t2;
    unsigned long long mask = __ballot(t2 == 1);
    if (t2 == 1) {
      int lane = tid & 63;
      unsigned long long lt = (lane == 0) ? 0ull : (~0ull >> (64 - lane));
      int rnk = __popcll(mask & lt);
      int leader = __ffsll((long long)mask) - 1;
      int base = 0;
      if (lane == leader) base = atomicAdd(cntF, __popcll(mask));
      base = __shfl(base, leader);
      listF[base + rnk] = s;
    }
  }
}

// ---------------- fused per-layer GEMM: all 4 type paths in one launch --------
// grid = 4*nb, nb = m/32. block range [0,nb): type1, [nb,2nb): type2,
// [2nb,3nb): type3, [3nb,4nb): type0. Each row's result -> temp[row] (bf16),
// NO atomics (segment reduction happens later over contiguous rows).
__global__ __launch_bounds__(256) void fused_gemm(
    const short* __restrict__ Abf, const int* __restrict__ om, int m,
    const int* __restrict__ lists, const int* __restrict__ counts,
    const short* __restrict__ Wp,
    const short* __restrict__ Wz, const short* __restrict__ Wzint,
    const short* __restrict__ Ws, const short* __restrict__ Wsint,
    short* __restrict__ temp, int nb) {
  int bt = (int)blockIdx.x / nb;        // 0..3
  int bi = (int)blockIdx.x % nb;
  int type = (bt == 3) ? 0 : (bt + 1);
  int n = counts[type];
  int rowbase = bi * 32;
  if (rowbase >= n) return;
  const int* list = lists + type * 65536;
  const int tid = threadIdx.x;

  if (type == 0) {
    // temp[row] = child0 row (bf16 copy) or zeros
    int lim = n - rowbase;
    if (lim > 32) lim = 32;
    for (int idx = tid; idx < lim * 32; idx += 256) {
      int e = rowbase + (idx >> 5);
      int q = idx & 31;
      int row = list[e];
      int c = om[row];
      bf16x8 v = {0, 0, 0, 0, 0, 0, 0, 0};
      if (c >= 0) v = *(const bf16x8*)(Abf + (size_t)c * 256 + q * 8);
      *(bf16x8*)(temp + (size_t)row * 256 + q * 8) = v;
    }
    return;
  }

  const int lane = tid & 63;
  const int wave = tid >> 6;
  const int colbase = wave * 64;
  const int lr = lane & 15;
  const int kg = lane >> 4;

  __shared__ __align__(16) short lds_t[32 * 256];  // 16 KB, XOR-swizzled

  f32x4 acc[2][4];
#pragma unroll
  for (int rt = 0; rt < 2; ++rt)
#pragma unroll
    for (int c = 0; c < 4; ++c) {
      f32x4 z = {0.f, 0.f, 0.f, 0.f};
      acc[rt][c] = z;
    }

  if (type == 1) {
    int src[2];
#pragma unroll
    for (int rt = 0; rt < 2; ++rt) {
      int i = rowbase + rt * 16 + lr;
      src[rt] = (i < n) ? om[list[i]] : -1;   // child 0
    }
#pragma unroll 2
    for (int ko = 0; ko < 256; ko += 32) {
      bf16x8 b[4];
#pragma unroll
      for (int c = 0; c < 4; ++c)
        b[c] = *(const bf16x8*)(Wp + (size_t)(colbase + c * 16 + lr) * 256 + ko + kg * 8);
#pragma unroll
      for (int rt = 0; rt < 2; ++rt) {
        bf16x8 a = {0, 0, 0, 0, 0, 0, 0, 0};
        if (src[rt] >= 0)
          a = *(const bf16x8*)(Abf + (size_t)src[rt] * 256 + ko + kg * 8);
#pragma unroll
        for (int c = 0; c < 4; ++c)
          acc[rt][c] = __builtin_amdgcn_mfma_f32_16x16x32_bf16(a, b[c], acc[rt][c], 0, 0, 0);
      }
    }
  } else {
    const short* W1 = (type == 2) ? Wz : Ws;
    const short* W2 = (type == 2) ? Wzint : Wsint;
    int cidx[2][4];
#pragma unroll
    for (int rt = 0; rt < 2; ++rt) {
      int i = rowbase + rt * 16 + lr;
      int row = (i < n) ? list[i] : -1;
#pragma unroll
      for (int k = 0; k < 4; ++k) cidx[rt][k] = (row >= 0) ? om[k * m + row] : -1;
    }
#pragma unroll
    for (int kc = 0; kc < 4; ++kc) {
      const short* W1k = W1 + (size_t)kc * 65536;
#pragma unroll 2
      for (int ko = 0; ko < 256; ko += 32) {
        bf16x8 b[4];
#pragma unroll
        for (int c = 0; c < 4; ++c)
          b[c] = *(const bf16x8*)(W1k + (size_t)(colbase + c * 16 + lr) * 256 + ko + kg * 8);
#pragma unroll
        for (int rt = 0; rt < 2; ++rt) {
          bf16x8 a = {0, 0, 0, 0, 0, 0, 0, 0};
          int ca = cidx[rt][kc];
          if (ca >= 0)
            a = *(const bf16x8*)(Abf + (size_t)ca * 256 + ko + kg * 8);
#pragma unroll
          for (int c = 0; c < 4; ++c)
            acc[rt][c] = __builtin_amdgcn_mfma_f32_16x16x32_bf16(a, b[c], acc[rt][c], 0, 0, 0);
        }
      }
    }
    // temp tile -> LDS (bf16), XOR-swizzled so GEMM2's row-reads are conflict-free
#pragma unroll
    for (int rt = 0; rt < 2; ++rt)
#pragma unroll
      for (int c = 0; c < 4; ++c) {
        int col = colbase + c * 16 + lr;
#pragma unroll
        for (int q = 0; q < 4; ++q) {
          int row = rt * 16 + kg * 4 + q;
          int off = (row * 512 + col * 2) ^ ((row & 7) << 4);
          *(short*)((char*)lds_t + off) = f2bf(acc[rt][c][q]);
        }
      }
    __syncthreads();
#pragma unroll
    for (int rt = 0; rt < 2; ++rt)
#pragma unroll
      for (int c = 0; c < 4; ++c) {
        f32x4 z = {0.f, 0.f, 0.f, 0.f};
        acc[rt][c] = z;
      }
#pragma unroll 2
    for (int ko = 0; ko < 256; ko += 32) {
      bf16x8 b[4];
#pragma unroll
      for (int c = 0; c < 4; ++c)
        b[c] = *(const bf16x8*)(W2 + (size_t)(colbase + c * 16 + lr) * 256 + ko + kg * 8);
#pragma unroll
      for (int rt = 0; rt < 2; ++rt) {
        int row = rt * 16 + lr;
        int off = (row * 512 + (ko + kg * 8) * 2) ^ ((row & 7) << 4);
        bf16x8 a = *(const bf16x8*)((char*)lds_t + off);
#pragma unroll
        for (int c = 0; c < 4; ++c)
          acc[rt][c] = __builtin_amdgcn_mfma_f32_16x16x32_bf16(a, b[c], acc[rt][c], 0, 0, 0);
      }
    }
  }

  // epilogue: plain bf16 stores to temp[list[i]]
#pragma unroll
  for (int rt = 0; rt < 2; ++rt) {
#pragma unroll
    for (int q = 0; q < 4; ++q) {
      int i2 = rowbase + rt * 16 + kg * 4 + q;
      if (i2 >= n) continue;
      int row = list[i2];
      short* dst = temp + (size_t)row * 256 + colbase + lr;
#pragma unroll
      for (int c = 0; c < 4; ++c) dst[c * 16] = f2bf(acc[rt][c][q]);
    }
  }
}

// ------- segment reduce (contiguous r rows) + ELU + write next/out ----------
__global__ __launch_bounds__(256) void reduce_kernel(const short* __restrict__ temp,
                                                     int r, int g,
                                                     const int* __restrict__ tm2,
                                                     float* __restrict__ outf,
                                                     short* __restrict__ outbf) {
  int idx = blockIdx.x * 256 + threadIdx.x;
  if (idx >= g * 32) return;
  int s = idx >> 5;
  int q = idx & 31;
  float acc[8];
#pragma unroll
  for (int k = 0; k < 8; ++k) acc[k] = 0.f;
  for (int j = 0; j < r; ++j) {
    bf16x8 v = *(const bf16x8*)(temp + (size_t)(s * r + j) * 256 + q * 8);
#pragma unroll
    for (int k = 0; k < 8; ++k) acc[k] += bf2f(v[k]);
  }
  if (tm2[s] != 0) {
#pragma unroll
    for (int k = 0; k < 8; ++k) acc[k] = acc[k] > 0.f ? acc[k] : (expf(acc[k]) - 1.f);
  }
  if (outf) {
    float4 f0 = {acc[0], acc[1], acc[2], acc[3]};
    float4 f1 = {acc[4], acc[5], acc[6], acc[7]};
    *(float4*)(outf + (size_t)s * 256 + q * 8) = f0;
    *(float4*)(outf + (size_t)s * 256 + q * 8 + 4) = f1;
  }
  if (outbf) {
    bf16x8 o;
#pragma unroll
    for (int k = 0; k < 8; ++k) o[k] = f2bf(acc[k]);
    *(bf16x8*)(outbf + (size_t)s * 256 + q * 8) = o;
  }
}

// -------- tm2==1 segments: rows = rows @ W_pf^T in place ----------
// SRC 0: bf16 buf (read+write). SRC 1: fp32 fbuf (read+write).
template <int SRC>
__global__ __launch_bounds__(256) void pf_gemm(short* __restrict__ buf,
                                               float* __restrict__ fbuf,
                                               const int* __restrict__ listF,
                                               const int* __restrict__ cnt,
                                               const short* __restrict__ Wpf) {
  int n = *cnt;
  int rowbase = blockIdx.x * 32;
  if (rowbase >= n) return;
  const int lane = threadIdx.x & 63;
  const int wave = threadIdx.x >> 6;
  const int colbase = wave * 64;
  const int lr = lane & 15;
  const int kg = lane >> 4;

  int src[2];
#pragma unroll
  for (int rt = 0; rt < 2; ++rt) {
    int i = rowbase + rt * 16 + lr;
    src[rt] = (i < n) ? listF[i] : -1;
  }

  f32x4 acc[2][4];
#pragma unroll
  for (int rt = 0; rt < 2; ++rt)
#pragma unroll
    for (int c = 0; c < 4; ++c) {
      f32x4 z = {0.f, 0.f, 0.f, 0.f};
      acc[rt][c] = z;
    }

#pragma unroll 2
  for (int ko = 0; ko < 256; ko += 32) {
    bf16x8 b[4];
#pragma unroll
    for (int c = 0; c < 4; ++c)
      b[c] = *(const bf16x8*)(Wpf + (size_t)(colbase + c * 16 + lr) * 256 + ko + kg * 8);
#pragma unroll
    for (int rt = 0; rt < 2; ++rt) {
      bf16x8 a = {0, 0, 0, 0, 0, 0, 0, 0};
      if (src[rt] >= 0) {
        if (SRC == 0) {
          a = *(const bf16x8*)(buf + (size_t)src[rt] * 256 + ko + kg * 8);
        } else {
          const float* p = fbuf + (size_t)src[rt] * 256 + ko + kg * 8;
          float4 u0 = *(const float4*)p;
          float4 u1 = *(const float4*)(p + 4);
          a[0] = f2bf(u0.x); a[1] = f2bf(u0.y); a[2] = f2bf(u0.z); a[3] = f2bf(u0.w);
          a[4] = f2bf(u1.x); a[5] = f2bf(u1.y); a[6] = f2bf(u1.z); a[7] = f2bf(u1.w);
        }
      }
#pragma unroll
      for (int c = 0; c < 4; ++c)
        acc[rt][c] = __builtin_amdgcn_mfma_f32_16x16x32_bf16(a, b[c], acc[rt][c], 0, 0, 0);
    }
  }

  __syncthreads();  // all waves done READING these rows before any wave overwrites

#pragma unroll
  for (int rt = 0; rt < 2; ++rt) {
#pragma unroll
    for (int q = 0; q < 4; ++q) {
      int i2 = rowbase + rt * 16 + kg * 4 + q;
      if (i2 >= n) continue;
      int c2 = listF[i2];
      if (SRC == 0) {
        short* db = buf + (size_t)c2 * 256 + colbase + lr;
#pragma unroll
        for (int c = 0; c < 4; ++c) db[c * 16] = f2bf(acc[rt][c][q]);
      } else {
        float* df = fbuf + (size_t)c2 * 256 + colbase + lr;
#pragma unroll
        for (int c = 0; c < 4; ++c) df[c * 16] = acc[rt][c][q];
      }
    }
  }
}

// ---------------- host driver ----------------
extern "C" void kernel_launch(void* const* d_in, const int* in_sizes, int n_in,
                              void* d_out, int out_size, void* d_ws, size_t ws_size,
                              hipStream_t stream) {
  const float* x = (const float*)d_in[0];
  const int* initial_map = (const int*)d_in[1];
  const int* om[3] = {(const int*)d_in[2], (const int*)d_in[5], (const int*)d_in[8]};
  const int* tmask[3] = {(const int*)d_in[4], (const int*)d_in[7], (const int*)d_in[10]};
  const float* W_z = (const float*)d_in[11];
  const float* W_z_int = (const float*)d_in[12];
  const float* W_s = (const float*)d_in[13];
  const float* W_s_int = (const float*)d_in[14];
  const float* W_p = (const float*)d_in[15];
  const float* W_pf = (const float*)d_in[16];

  char* base = (char*)d_ws;
  // liveness-packed layout (~67 MB total):
  short* d0bf  = (short*)(base);               // 32 MB: gather -> l0 fused
  short* temp0 = (short*)(base + 33554432);    // 32 MB: l0 fused -> l0 reduce
  short* d1bf  = (short*)(base);               // 16 MB: l0 reduce -> l1 fused (d0bf dead)
  short* temp1 = (short*)(base + 16777216);    // 16 MB: l1 fused -> l1 reduce
  short* d2bf  = (short*)(base + 33554432);    //  4 MB: l1 reduce -> l2 fused (temp0 dead)
  short* temp2 = (short*)(base + 37748736);    //  4 MB: l2 fused -> l2 reduce
  short* Wbf   = (short*)(base + 67108864);    // 1.5 MB
  int* lists   = (int*)(base + 68681728);      // 1 MB (4 x 65536)
  int* listF   = (int*)(base + 69730304);      // 128 KB
  int* tm2     = (int*)(base + 69861376);      // 128 KB
  int* counts  = (int*)(base + 69992448);      // 256 B

  const short* Wz_bf    = Wbf + 0;
  const short* Wzint_bf = Wbf + 262144;
  const short* Ws_bf    = Wbf + 327680;
  const short* Wsint_bf = Wbf + 589824;
  const short* Wp_bf    = Wbf + 655360;
  const short* Wpf_bf   = Wbf + 720896;

  hipLaunchKernelGGL(cvt_w_kernel, dim3(768), dim3(256), 0, stream, W_z, W_z_int, W_s,
                     W_s_int, W_p, W_pf, Wbf);
  hipLaunchKernelGGL(gather_cvt_kernel, dim3(2048), dim3(256), 0, stream,
                     (const float4*)x, initial_map, (short4v*)d0bf, 65536);

  const int Ms[3] = {65536, 32768, 8192};
  const int Gs[3] = {32768, 8192, 2048};
  const short* dinbf[3] = {d0bf, d1bf, d2bf};
  short* tempL[3] = {temp0, temp1, temp2};
  short* nextbf[3] = {d1bf, d2bf, nullptr};

  for (int l = 0; l < 3; ++l) {
    int m = Ms[l], g = Gs[l], r = m / g;
    hipMemsetAsync(counts, 0, 256, stream);

    hipLaunchKernelGGL(bucket_seg_kernel, dim3(m / 256), dim3(256), 0, stream,
                       tmask[l], r, g, lists, counts, tm2, listF, counts + 4, m);

    int nb = m / 32;
    hipLaunchKernelGGL(fused_gemm, dim3(4 * nb), dim3(256), 0, stream, dinbf[l], om[l],
                       m, lists, counts, Wp_bf, Wz_bf, Wzint_bf, Ws_bf, Wsint_bf,
                       tempL[l], nb);

    hipLaunchKernelGGL(reduce_kernel, dim3(g * 32 / 256), dim3(256), 0, stream,
                       tempL[l], r, g, tm2, (l == 2) ? (float*)d_out : nullptr,
                       nextbf[l]);

    if (l < 2)
      hipLaunchKernelGGL((pf_gemm<0>), dim3(g / 32), dim3(256), 0, stream, nextbf[l],
                         (float*)nullptr, listF, counts + 4, Wpf_bf);
    else
      hipLaunchKernelGGL((pf_gemm<1>), dim3(g / 32), dim3(256), 0, stream,
                         (short*)nullptr, (float*)d_out, listF, counts + 4, Wpf_bf);
  }
}

// Round 6
// 278.753 us; speedup vs baseline: 11.2559x; 1.3974x over previous
//
#include <hip/hip_runtime.h>
#include <math.h>

#define H 256

typedef __attribute__((ext_vector_type(8))) short bf16x8;
typedef __attribute__((ext_vector_type(4))) float f32x4;
typedef __attribute__((ext_vector_type(4))) short short4v;

__device__ __forceinline__ short f2bf(float f) {
  union { float f; unsigned u; } x;
  x.f = f;
  unsigned r = x.u + 0x7fffu + ((x.u >> 16) & 1u);
  return (short)(r >> 16);
}
__device__ __forceinline__ float bf2f(short s) {
  union { float f; unsigned u; } x;
  x.u = ((unsigned)(unsigned short)s) << 16;
  return x.f;
}

// ---------------- gather + convert: d0bf[i] = bf16(x[map[i]]) ----------------
__global__ __launch_bounds__(256) void gather_cvt_kernel(const float4* __restrict__ x,
                                                         const int* __restrict__ map,
                                                         short4v* __restrict__ out, int n) {
  int total = n * (H / 4);
  for (int idx = blockIdx.x * blockDim.x + threadIdx.x; idx < total;
       idx += gridDim.x * blockDim.x) {
    int e = idx >> 6;
    int q = idx & 63;
    float4 v = x[(size_t)map[e] * 64 + q];
    short4v s;
    s[0] = f2bf(v.x); s[1] = f2bf(v.y); s[2] = f2bf(v.z); s[3] = f2bf(v.w);
    out[idx] = s;
  }
}

// ---------------- convert all 6 weights fp32 -> bf16 (original [o][h] layout) ----
__global__ __launch_bounds__(256) void cvt_w_kernel(const float* __restrict__ s0,
                                                    const float* __restrict__ s1,
                                                    const float* __restrict__ s2,
                                                    const float* __restrict__ s3,
                                                    const float* __restrict__ s4,
                                                    const float* __restrict__ s5,
                                                    short* __restrict__ dst) {
  int i4 = blockIdx.x * blockDim.x + threadIdx.x;
  if (i4 >= 196608) return;
  int e = i4 * 4;
  const float* src;
  int off;
  if (e < 262144)      { src = s0; off = e; }
  else if (e < 327680) { src = s1; off = e - 262144; }
  else if (e < 589824) { src = s2; off = e - 327680; }
  else if (e < 655360) { src = s3; off = e - 589824; }
  else if (e < 720896) { src = s4; off = e - 655360; }
  else                 { src = s5; off = e - 720896; }
  float4 v = *(const float4*)(src + off);
  short4v o;
  o[0] = f2bf(v.x); o[1] = f2bf(v.y); o[2] = f2bf(v.z); o[3] = f2bf(v.w);
  *(short4v*)(dst + e) = o;
}

// ------- bucket rows by type (LDS-aggregated) + per-segment tm2 + listF -------
__global__ __launch_bounds__(256) void bucket_seg_kernel(const int* __restrict__ tmask,
                                                         int r, int g,
                                                         int* __restrict__ lists,
                                                         int* __restrict__ counts,
                                                         int* __restrict__ tm2,
                                                         int* __restrict__ listF,
                                                         int* __restrict__ cntF, int m) {
  __shared__ int lc[4];
  __shared__ int lbase[4];
  int tid = threadIdx.x;
  if (tid < 4) lc[tid] = 0;
  __syncthreads();
  int i = blockIdx.x * 256 + tid;
  int t = 0, rank = 0;
  bool ok = i < m;
  if (ok) {
    t = tmask[i];
    rank = atomicAdd(&lc[t], 1);
  }
  __syncthreads();
  if (tid < 4) lbase[tid] = atomicAdd(&counts[tid], lc[tid]);
  __syncthreads();
  if (ok) lists[t * 65536 + lbase[t] + rank] = i;

  // segment work: ids < g (g is a multiple of 256 -> full waves)
  int s = i;
  if (s < g) {
    int t2 = 0;
    for (int j = 0; j < r; ++j) {
      int tt = tmask[s * r + j];
      t2 = tt > t2 ? tt : t2;
    }
    tm2[s] = t2;
    unsigned long long mask = __ballot(t2 == 1);
    if (t2 == 1) {
      int lane = tid & 63;
      unsigned long long lt = (lane == 0) ? 0ull : (~0ull >> (64 - lane));
      int rnk = __popcll(mask & lt);
      int leader = __ffsll((long long)mask) - 1;
      int base = 0;
      if (lane == leader) base = atomicAdd(cntF, __popcll(mask));
      base = __shfl(base, leader);
      listF[base + rnk] = s;
    }
  }
}

// ---------------- fused per-layer GEMM: all 4 type paths in one launch --------
// grid = 4*nb, nb = ceil(m/64). BM=64 rows/block, 4 waves x 64 cols.
// A rows staged once per block in LDS (XOR-swizzled); B direct from L2.
// Each row's result -> temp[row] (bf16), no atomics.
__global__ __launch_bounds__(256) void fused_gemm(
    const short* __restrict__ Abf, const int* __restrict__ om, int m,
    const int* __restrict__ lists, const int* __restrict__ counts,
    const short* __restrict__ Wp,
    const short* __restrict__ Wz, const short* __restrict__ Wzint,
    const short* __restrict__ Ws, const short* __restrict__ Wsint,
    short* __restrict__ temp, int nb) {
  int bt = (int)blockIdx.x / nb;        // 0..3
  int bi = (int)blockIdx.x % nb;
  int type = (bt == 3) ? 0 : (bt + 1);
  int n = counts[type];
  int rowbase = bi * 64;
  if (rowbase >= n) return;
  const int* list = lists + type * 65536;
  const int tid = threadIdx.x;

  if (type == 0) {
    // temp[row] = child0 row (bf16 copy) or zeros
    int lim = n - rowbase;
    if (lim > 64) lim = 64;
    for (int idx = tid; idx < lim * 32; idx += 256) {
      int e = rowbase + (idx >> 5);
      int q = idx & 31;
      int row = list[e];
      int c = om[row];
      bf16x8 v = {0, 0, 0, 0, 0, 0, 0, 0};
      if (c >= 0) v = *(const bf16x8*)(Abf + (size_t)c * 256 + q * 8);
      *(bf16x8*)(temp + (size_t)row * 256 + q * 8) = v;
    }
    return;
  }

  const int lane = tid & 63;
  const int wave = tid >> 6;
  const int colbase = wave * 64;
  const int lr = lane & 15;
  const int kg = lane >> 4;

  __shared__ __align__(16) char lds[64 * 512];  // 32 KB A-stage / GEMM2 temp
  __shared__ int sChild[4][64];

  const int nch = (type == 1) ? 1 : 4;
  // fill child indices (one per local row per kc)
  if (tid < 64) {
    int i = rowbase + tid;
    int row = (i < n) ? list[i] : -1;
    if (type == 1) {
      sChild[0][tid] = (row >= 0) ? om[row] : -1;
    } else {
#pragma unroll
      for (int k = 0; k < 4; ++k) sChild[k][tid] = (row >= 0) ? om[k * m + row] : -1;
    }
  }

  f32x4 acc[4][4];
#pragma unroll
  for (int rt = 0; rt < 4; ++rt)
#pragma unroll
    for (int c = 0; c < 4; ++c) {
      f32x4 z = {0.f, 0.f, 0.f, 0.f};
      acc[rt][c] = z;
    }

  const short* W1 = (type == 1) ? Wp : ((type == 2) ? Wz : Ws);
  const short* W2 = (type == 2) ? Wzint : Wsint;

  __syncthreads();  // sChild ready

  for (int kc = 0; kc < nch; ++kc) {
    // stage A_kc: 64 rows x 512 B, coalesced; zero for missing children
#pragma unroll
    for (int it = 0; it < 8; ++it) {
      int idx = it * 256 + tid;
      int row = idx >> 5;        // 0..63
      int chunk = idx & 31;      // 16-B units
      int c = sChild[kc][row];
      bf16x8 v = {0, 0, 0, 0, 0, 0, 0, 0};
      if (c >= 0) v = *(const bf16x8*)(Abf + (size_t)c * 256 + chunk * 8);
      int off = (row * 512 + chunk * 16) ^ ((row & 7) << 4);
      *(bf16x8*)(lds + off) = v;
    }
    __syncthreads();

    const short* W1k = W1 + (size_t)kc * 65536;
#pragma unroll 2
    for (int ko = 0; ko < 8; ++ko) {
      bf16x8 b[4];
#pragma unroll
      for (int c = 0; c < 4; ++c)
        b[c] = *(const bf16x8*)(W1k + (size_t)(colbase + c * 16 + lr) * 256 + ko * 32 + kg * 8);
#pragma unroll
      for (int rt = 0; rt < 4; ++rt) {
        int row = rt * 16 + lr;
        int off = (row * 512 + ko * 64 + kg * 16) ^ ((row & 7) << 4);
        bf16x8 a = *(const bf16x8*)(lds + off);
#pragma unroll
        for (int c = 0; c < 4; ++c)
          acc[rt][c] = __builtin_amdgcn_mfma_f32_16x16x32_bf16(a, b[c], acc[rt][c], 0, 0, 0);
      }
    }
    __syncthreads();  // done reading this kc's A before restaging
  }

  if (type != 1) {
    // GEMM2: acc (bf16, via LDS) @ W2^T
#pragma unroll
    for (int rt = 0; rt < 4; ++rt)
#pragma unroll
      for (int c = 0; c < 4; ++c) {
        int col = colbase + c * 16 + lr;
#pragma unroll
        for (int q = 0; q < 4; ++q) {
          int row = rt * 16 + kg * 4 + q;
          int off = (row * 512 + col * 2) ^ ((row & 7) << 4);
          *(short*)(lds + off) = f2bf(acc[rt][c][q]);
        }
      }
    __syncthreads();
#pragma unroll
    for (int rt = 0; rt < 4; ++rt)
#pragma unroll
      for (int c = 0; c < 4; ++c) {
        f32x4 z = {0.f, 0.f, 0.f, 0.f};
        acc[rt][c] = z;
      }
#pragma unroll 2
    for (int ko = 0; ko < 8; ++ko) {
      bf16x8 b[4];
#pragma unroll
      for (int c = 0; c < 4; ++c)
        b[c] = *(const bf16x8*)(W2 + (size_t)(colbase + c * 16 + lr) * 256 + ko * 32 + kg * 8);
#pragma unroll
      for (int rt = 0; rt < 4; ++rt) {
        int row = rt * 16 + lr;
        int off = (row * 512 + ko * 64 + kg * 16) ^ ((row & 7) << 4);
        bf16x8 a = *(const bf16x8*)(lds + off);
#pragma unroll
        for (int c = 0; c < 4; ++c)
          acc[rt][c] = __builtin_amdgcn_mfma_f32_16x16x32_bf16(a, b[c], acc[rt][c], 0, 0, 0);
      }
    }
  }

  // epilogue: plain bf16 stores to temp[list[i]]
#pragma unroll
  for (int rt = 0; rt < 4; ++rt) {
#pragma unroll
    for (int q = 0; q < 4; ++q) {
      int i2 = rowbase + rt * 16 + kg * 4 + q;
      if (i2 >= n) continue;
      int row = list[i2];
      short* dst = temp + (size_t)row * 256 + colbase + lr;
#pragma unroll
      for (int c = 0; c < 4; ++c) dst[c * 16] = f2bf(acc[rt][c][q]);
    }
  }
}

// ------- segment reduce (contiguous r rows) + ELU + write next/out ----------
__global__ __launch_bounds__(256) void reduce_kernel(const short* __restrict__ temp,
                                                     int r, int g,
                                                     const int* __restrict__ tm2,
                                                     float* __restrict__ outf,
                                                     short* __restrict__ outbf) {
  int idx = blockIdx.x * 256 + threadIdx.x;
  if (idx >= g * 32) return;
  int s = idx >> 5;
  int q = idx & 31;
  float acc[8];
#pragma unroll
  for (int k = 0; k < 8; ++k) acc[k] = 0.f;
  for (int j = 0; j < r; ++j) {
    bf16x8 v = *(const bf16x8*)(temp + (size_t)(s * r + j) * 256 + q * 8);
#pragma unroll
    for (int k = 0; k < 8; ++k) acc[k] += bf2f(v[k]);
  }
  if (tm2[s] != 0) {
#pragma unroll
    for (int k = 0; k < 8; ++k) acc[k] = acc[k] > 0.f ? acc[k] : (expf(acc[k]) - 1.f);
  }
  if (outf) {
    float4 f0 = {acc[0], acc[1], acc[2], acc[3]};
    float4 f1 = {acc[4], acc[5], acc[6], acc[7]};
    *(float4*)(outf + (size_t)s * 256 + q * 8) = f0;
    *(float4*)(outf + (size_t)s * 256 + q * 8 + 4) = f1;
  }
  if (outbf) {
    bf16x8 o;
#pragma unroll
    for (int k = 0; k < 8; ++k) o[k] = f2bf(acc[k]);
    *(bf16x8*)(outbf + (size_t)s * 256 + q * 8) = o;
  }
}

// -------- tm2==1 segments: rows = rows @ W_pf^T in place ----------
// SRC 0: bf16 buf (read+write). SRC 1: fp32 fbuf (read+write).
template <int SRC>
__global__ __launch_bounds__(256) void pf_gemm(short* __restrict__ buf,
                                               float* __restrict__ fbuf,
                                               const int* __restrict__ listF,
                                               const int* __restrict__ cnt,
                                               const short* __restrict__ Wpf) {
  int n = *cnt;
  int rowbase = blockIdx.x * 32;
  if (rowbase >= n) return;
  const int lane = threadIdx.x & 63;
  const int wave = threadIdx.x >> 6;
  const int colbase = wave * 64;
  const int lr = lane & 15;
  const int kg = lane >> 4;

  int src[2];
#pragma unroll
  for (int rt = 0; rt < 2; ++rt) {
    int i = rowbase + rt * 16 + lr;
    src[rt] = (i < n) ? listF[i] : -1;
  }

  f32x4 acc[2][4];
#pragma unroll
  for (int rt = 0; rt < 2; ++rt)
#pragma unroll
    for (int c = 0; c < 4; ++c) {
      f32x4 z = {0.f, 0.f, 0.f, 0.f};
      acc[rt][c] = z;
    }

#pragma unroll 2
  for (int ko = 0; ko < 256; ko += 32) {
    bf16x8 b[4];
#pragma unroll
    for (int c = 0; c < 4; ++c)
      b[c] = *(const bf16x8*)(Wpf + (size_t)(colbase + c * 16 + lr) * 256 + ko + kg * 8);
#pragma unroll
    for (int rt = 0; rt < 2; ++rt) {
      bf16x8 a = {0, 0, 0, 0, 0, 0, 0, 0};
      if (src[rt] >= 0) {
        if (SRC == 0) {
          a = *(const bf16x8*)(buf + (size_t)src[rt] * 256 + ko + kg * 8);
        } else {
          const float* p = fbuf + (size_t)src[rt] * 256 + ko + kg * 8;
          float4 u0 = *(const float4*)p;
          float4 u1 = *(const float4*)(p + 4);
          a[0] = f2bf(u0.x); a[1] = f2bf(u0.y); a[2] = f2bf(u0.z); a[3] = f2bf(u0.w);
          a[4] = f2bf(u1.x); a[5] = f2bf(u1.y); a[6] = f2bf(u1.z); a[7] = f2bf(u1.w);
        }
      }
#pragma unroll
      for (int c = 0; c < 4; ++c)
        acc[rt][c] = __builtin_amdgcn_mfma_f32_16x16x32_bf16(a, b[c], acc[rt][c], 0, 0, 0);
    }
  }

  __syncthreads();  // all waves done READING these rows before any wave overwrites

#pragma unroll
  for (int rt = 0; rt < 2; ++rt) {
#pragma unroll
    for (int q = 0; q < 4; ++q) {
      int i2 = rowbase + rt * 16 + kg * 4 + q;
      if (i2 >= n) continue;
      int c2 = listF[i2];
      if (SRC == 0) {
        short* db = buf + (size_t)c2 * 256 + colbase + lr;
#pragma unroll
        for (int c = 0; c < 4; ++c) db[c * 16] = f2bf(acc[rt][c][q]);
      } else {
        float* df = fbuf + (size_t)c2 * 256 + colbase + lr;
#pragma unroll
        for (int c = 0; c < 4; ++c) df[c * 16] = acc[rt][c][q];
      }
    }
  }
}

// ---------------- host driver ----------------
extern "C" void kernel_launch(void* const* d_in, const int* in_sizes, int n_in,
                              void* d_out, int out_size, void* d_ws, size_t ws_size,
                              hipStream_t stream) {
  const float* x = (const float*)d_in[0];
  const int* initial_map = (const int*)d_in[1];
  const int* om[3] = {(const int*)d_in[2], (const int*)d_in[5], (const int*)d_in[8]};
  const int* tmask[3] = {(const int*)d_in[4], (const int*)d_in[7], (const int*)d_in[10]};
  const float* W_z = (const float*)d_in[11];
  const float* W_z_int = (const float*)d_in[12];
  const float* W_s = (const float*)d_in[13];
  const float* W_s_int = (const float*)d_in[14];
  const float* W_p = (const float*)d_in[15];
  const float* W_pf = (const float*)d_in[16];

  char* base = (char*)d_ws;
  // liveness-packed layout (~67 MB total):
  short* d0bf  = (short*)(base);               // 32 MB: gather -> l0 fused
  short* temp0 = (short*)(base + 33554432);    // 32 MB: l0 fused -> l0 reduce
  short* d1bf  = (short*)(base);               // 16 MB: l0 reduce -> l1 fused (d0bf dead)
  short* temp1 = (short*)(base + 16777216);    // 16 MB: l1 fused -> l1 reduce
  short* d2bf  = (short*)(base + 33554432);    //  4 MB: l1 reduce -> l2 fused (temp0 dead)
  short* temp2 = (short*)(base + 37748736);    //  4 MB: l2 fused -> l2 reduce
  short* Wbf   = (short*)(base + 67108864);    // 1.5 MB
  int* lists   = (int*)(base + 68681728);      // 1 MB (4 x 65536)
  int* listF   = (int*)(base + 69730304);      // 128 KB
  int* tm2     = (int*)(base + 69861376);      // 128 KB
  int* counts  = (int*)(base + 69992448);      // 256 B

  const short* Wz_bf    = Wbf + 0;
  const short* Wzint_bf = Wbf + 262144;
  const short* Ws_bf    = Wbf + 327680;
  const short* Wsint_bf = Wbf + 589824;
  const short* Wp_bf    = Wbf + 655360;
  const short* Wpf_bf   = Wbf + 720896;

  hipLaunchKernelGGL(cvt_w_kernel, dim3(768), dim3(256), 0, stream, W_z, W_z_int, W_s,
                     W_s_int, W_p, W_pf, Wbf);
  hipLaunchKernelGGL(gather_cvt_kernel, dim3(2048), dim3(256), 0, stream,
                     (const float4*)x, initial_map, (short4v*)d0bf, 65536);

  const int Ms[3] = {65536, 32768, 8192};
  const int Gs[3] = {32768, 8192, 2048};
  const short* dinbf[3] = {d0bf, d1bf, d2bf};
  short* tempL[3] = {temp0, temp1, temp2};
  short* nextbf[3] = {d1bf, d2bf, nullptr};

  for (int l = 0; l < 3; ++l) {
    int m = Ms[l], g = Gs[l], r = m / g;
    hipMemsetAsync(counts, 0, 256, stream);

    hipLaunchKernelGGL(bucket_seg_kernel, dim3(m / 256), dim3(256), 0, stream,
                       tmask[l], r, g, lists, counts, tm2, listF, counts + 4, m);

    int nb = (m + 63) / 64;
    hipLaunchKernelGGL(fused_gemm, dim3(4 * nb), dim3(256), 0, stream, dinbf[l], om[l],
                       m, lists, counts, Wp_bf, Wz_bf, Wzint_bf, Ws_bf, Wsint_bf,
                       tempL[l], nb);

    hipLaunchKernelGGL(reduce_kernel, dim3(g * 32 / 256), dim3(256), 0, stream,
                       tempL[l], r, g, tm2, (l == 2) ? (float*)d_out : nullptr,
                       nextbf[l]);

    if (l < 2)
      hipLaunchKernelGGL((pf_gemm<0>), dim3(g / 32), dim3(256), 0, stream, nextbf[l],
                         (float*)nullptr, listF, counts + 4, Wpf_bf);
    else
      hipLaunchKernelGGL((pf_gemm<1>), dim3(g / 32), dim3(256), 0, stream,
                         (short*)nullptr, (float*)d_out, listF, counts + 4, Wpf_bf);
  }
}